// Round 7
// baseline (8666.392 us; speedup 1.0000x reference)
//
#include <hip/hip_runtime.h>

#define TT 2048
#define HH 512
#define EE 512
#define NTAGS 48
#define G4 2048   // 4*HH
#define CANARY 1.0e30f

typedef float f4 __attribute__((ext_vector_type(4)));
typedef float f2 __attribute__((ext_vector_type(2)));

// workspace byte offsets
#define OFF_XW    0ULL                                      // [2][TT][G4] f32 = 32 MB
#define OFF_HCAT  (OFF_XW   + 2ULL*TT*G4*4ULL)              // [TT][1024] f32 = 8 MB
#define OFF_FRM   (OFF_HCAT + (unsigned long long)TT*1024ULL*4ULL) // [TT][48] f32
#define OFF_HBUF  (OFF_FRM  + (unsigned long long)TT*NTAGS*4ULL)   // [2][4][HH] f32 (canary slots)
#define OFF_BP    (OFF_HBUF + 2ULL*4ULL*HH*4ULL)            // [TT][48] u8

// ---------------------------------------------------------------------------
// K1: xW[dir][t][r] = sum_e embed[words[t]][e]*Wih[dir][r][e] + bih[r]+bhh[r]
// 64x64 tile, 256 threads, 4x4 micro-tile, K-chunk 32. Also canary-fills the
// LSTM h exchange slots.
// ---------------------------------------------------------------------------
__global__ __launch_bounds__(256) void k_xw(
    const int* __restrict__ words, const float* __restrict__ embed,
    const float* __restrict__ WihF, const float* __restrict__ WihB,
    const float* __restrict__ bihF, const float* __restrict__ bhhF,
    const float* __restrict__ bihB, const float* __restrict__ bhhB,
    float* __restrict__ xw, float* __restrict__ hbuf)
{
    const int tid = threadIdx.x;
    const int bx = blockIdx.x, by = blockIdx.y, dir = blockIdx.z;

    if (bx == 0 && by == 0) {                   // one block per dir: canary fill
        for (int j = tid; j < 4*HH; j += 256)
            hbuf[dir*4*HH + j] = CANARY;
    }

    const float* Wih = dir ? WihB : WihF;
    const float* bi  = dir ? bihB : bihF;
    const float* bh  = dir ? bhhB : bhhF;

    __shared__ float sa[32][64];
    __shared__ float sb[32][64];
    __shared__ int   wds[64];
    if (tid < 64) wds[tid] = words[by*64 + tid];
    const int tx = tid & 15, ty = tid >> 4;
    float acc[4][4] = {};
    __syncthreads();

    for (int k0 = 0; k0 < EE; k0 += 32) {
        #pragma unroll
        for (int u = 0; u < 2; u++) {
            int idx = tid*2 + u;            // 0..511
            int row = idx >> 3, kq = idx & 7;
            float4 av = *(const float4*)&embed[(size_t)wds[row]*EE + k0 + kq*4];
            float4 bv = *(const float4*)&Wih[(size_t)(bx*64 + row)*EE + k0 + kq*4];
            sa[kq*4+0][row] = av.x; sa[kq*4+1][row] = av.y;
            sa[kq*4+2][row] = av.z; sa[kq*4+3][row] = av.w;
            sb[kq*4+0][row] = bv.x; sb[kq*4+1][row] = bv.y;
            sb[kq*4+2][row] = bv.z; sb[kq*4+3][row] = bv.w;
        }
        __syncthreads();
        #pragma unroll
        for (int k = 0; k < 32; k++) {
            float4 a = *(const float4*)&sa[k][ty*4];
            float4 b = *(const float4*)&sb[k][tx*4];
            acc[0][0] += a.x*b.x; acc[0][1] += a.x*b.y; acc[0][2] += a.x*b.z; acc[0][3] += a.x*b.w;
            acc[1][0] += a.y*b.x; acc[1][1] += a.y*b.y; acc[1][2] += a.y*b.z; acc[1][3] += a.y*b.w;
            acc[2][0] += a.z*b.x; acc[2][1] += a.z*b.y; acc[2][2] += a.z*b.z; acc[2][3] += a.z*b.w;
            acc[3][0] += a.w*b.x; acc[3][1] += a.w*b.y; acc[3][2] += a.w*b.z; acc[3][3] += a.w*b.w;
        }
        __syncthreads();
    }

    float* outp = xw + (size_t)dir*TT*G4;
    const int rbase = bx*64 + tx*4;
    float4 bi4 = *(const float4*)&bi[rbase];
    float4 bh4 = *(const float4*)&bh[rbase];
    float4 bias = make_float4(bi4.x+bh4.x, bi4.y+bh4.y, bi4.z+bh4.z, bi4.w+bh4.w);
    #pragma unroll
    for (int i = 0; i < 4; i++) {
        int t = by*64 + ty*4 + i;
        float4 v = make_float4(acc[i][0]+bias.x, acc[i][1]+bias.y,
                               acc[i][2]+bias.z, acc[i][3]+bias.w);
        *(float4*)&outp[(size_t)t*G4 + rbase] = v;
    }
}

// ---------------------------------------------------------------------------
// K2: Bi-LSTM recurrence, BOTH directions interleaved in each WG so dir0's
// LLC store->visibility latency hides under dir1's compute. 32 WGs x 512 thr;
// WG w owns h-outputs [16w,16w+16) of both dirs. Thread (v,o,g,k8) holds one
// gate-row's 64-float K-slice per dir (128 f32 VGPRs total, keep-live).
// Per step: dot0 -> gates0 -> store h0 (fire&forget) -> dot1 -> gates1 ->
// store h1 -> xv prefetch -> waves0-1 poll dir0 / waves2-3 poll dir1
// (dwordx4 sc0sc1, sleep(1)) -> restage LDS -> one barrier.
// Canary 4-slot rotation + single per-step vmcnt(0) ordering = round-3
// proven protocol (vmcnt covers both dirs' 2-step-old canary resets).
// LDS: 68-float chunk padding; reads are 8-way same-address broadcast,
// banks 4*(k8+t)%32 -> conflict-free.
// ---------------------------------------------------------------------------
__global__ __launch_bounds__(512, 2) void k_lstm(
    const float* __restrict__ WhhF, const float* __restrict__ WhhB,
    const float* __restrict__ h0, const float* __restrict__ cinit,
    const float* __restrict__ xw,
    float* __restrict__ hbuf, float* __restrict__ hcat)
{
    const int w   = blockIdx.x;          // 0..31
    const int tid = threadIdx.x;
    const int v   = tid >> 6;            // wave 0..7
    const int l   = tid & 63;
    const int o   = l >> 5;              // 0..1: which h-output of the wave
    const int g   = (l >> 3) & 3;        // gate 0:i 1:f 2:g 3:o
    const int k8  = l & 7;               // K-octant (64 floats)
    const int hidx = w*16 + v*2 + o;     // global h index [0,512)
    const int row  = g*HH + hidx;        // Whh row

    float* hb0 = hbuf;                   // dir0 [4][HH]
    float* hb1 = hbuf + 4*HH;            // dir1
    const float* xw0 = xw;
    const float* xw1 = xw + (size_t)TT*G4;

    // weights, both dirs: 16 float4 each (128 VGPR), keep-live
    float4 w0[16], w1[16];
    {
        const float4* p0 = (const float4*)&WhhF[(size_t)row*HH + k8*64];
        const float4* p1 = (const float4*)&WhhB[(size_t)row*HH + k8*64];
        #pragma unroll
        for (int t = 0; t < 16; t++) { w0[t] = p0[t]; w1[t] = p1[t]; }
        #pragma unroll
        for (int t = 0; t < 16; t++) {
            asm volatile("" : "+v"(w0[t].x), "+v"(w0[t].y), "+v"(w0[t].z), "+v"(w0[t].w));
            asm volatile("" : "+v"(w1[t].x), "+v"(w1[t].y), "+v"(w1[t].z), "+v"(w1[t].w));
        }
    }
    float c0r = cinit[0*HH + hidx];      // redundant across the 32 lanes of o
    float c1r = cinit[1*HH + hidx];

    // [buf][dir][8 chunks x 68 floats]
    __shared__ __align__(16) float hsh[2][2][8*68];
    {
        int ch = tid >> 6, of = tid & 63;
        hsh[0][0][ch*68 + of] = h0[0*HH + tid];
        hsh[0][1][ch*68 + of] = h0[1*HH + tid];
    }
    __syncthreads();

    float xv0 = 0.f, xv1 = 0.f;
    if (k8 == 0) {
        xv0 = xw0[(size_t)0*G4 + row];            // dir0 t=0
        xv1 = xw1[(size_t)(TT-1)*G4 + row];       // dir1 t=TT-1
    }

    const int ob = l & 32;               // o-group base lane

    for (int s = 0; s < TT; s++) {
        // ================= dir 0 =================
        float h0n;
        {
            const float* hc = &hsh[s & 1][0][k8*68];
            float p0=0.f,p1=0.f,p2=0.f,p3=0.f;
            #pragma unroll
            for (int t = 0; t < 16; t++) {
                float4 hv = *(const float4*)&hc[4*t];
                p0 += w0[t].x*hv.x; p1 += w0[t].y*hv.y;
                p2 += w0[t].z*hv.z; p3 += w0[t].w*hv.w;
            }
            float p = (p0+p1)+(p2+p3);
            if (k8 == 0) p += xv0;
            p += __shfl_xor(p, 1); p += __shfl_xor(p, 2); p += __shfl_xor(p, 4);
            float gi = __shfl(p, ob+0),  gf = __shfl(p, ob+8);
            float gg = __shfl(p, ob+16), go = __shfl(p, ob+24);
            float i_ = 1.f/(1.f + expf(-gi));
            float f_ = 1.f/(1.f + expf(-gf));
            float g_ = tanhf(gg);
            float o_ = 1.f/(1.f + expf(-go));
            c0r = f_*c0r + i_*g_;
            h0n = o_*tanhf(c0r);
        }
        {   // producer: lane 0 per wave, 2 floats (o=0,1)
            float ha = __shfl(h0n, 0), hbv = __shfl(h0n, 32);
            if (l == 0) {
                f2 pack = {ha, hbv};
                const int b2 = w*16 + v*2;
                // single per-step ordering point: drains BOTH dirs' canary
                // resets issued at step s-2 (same lane) before any h-store
                asm volatile("s_waitcnt vmcnt(0)" ::: "memory");
                if (s+1 < TT) {
                    const float* ah = &hb0[((s+1)&3)*HH + b2];
                    const float* ac = &hb0[((s+3)&3)*HH + b2];
                    f2 can = {CANARY, CANARY};
                    asm volatile("global_store_dwordx2 %0, %1, off sc0 sc1"
                                 :: "v"(ah), "v"(pack) : "memory");
                    asm volatile("global_store_dwordx2 %0, %1, off sc0 sc1"
                                 :: "v"(ac), "v"(can) : "memory");
                }
                *(f2*)&hcat[(size_t)s*1024 + 0*HH + b2] = pack;   // time0 = s
            }
        }

        // ================= dir 1 ================= (hides dir0 store latency)
        float h1n;
        {
            const float* hc = &hsh[s & 1][1][k8*68];
            float p0=0.f,p1=0.f,p2=0.f,p3=0.f;
            #pragma unroll
            for (int t = 0; t < 16; t++) {
                float4 hv = *(const float4*)&hc[4*t];
                p0 += w1[t].x*hv.x; p1 += w1[t].y*hv.y;
                p2 += w1[t].z*hv.z; p3 += w1[t].w*hv.w;
            }
            float p = (p0+p1)+(p2+p3);
            if (k8 == 0) p += xv1;
            p += __shfl_xor(p, 1); p += __shfl_xor(p, 2); p += __shfl_xor(p, 4);
            float gi = __shfl(p, ob+0),  gf = __shfl(p, ob+8);
            float gg = __shfl(p, ob+16), go = __shfl(p, ob+24);
            float i_ = 1.f/(1.f + expf(-gi));
            float f_ = 1.f/(1.f + expf(-gf));
            float g_ = tanhf(gg);
            float o_ = 1.f/(1.f + expf(-go));
            c1r = f_*c1r + i_*g_;
            h1n = o_*tanhf(c1r);
        }
        {
            float ha = __shfl(h1n, 0), hbv = __shfl(h1n, 32);
            if (l == 0) {
                f2 pack = {ha, hbv};
                const int b2 = w*16 + v*2;
                // no wait needed: step-s vmcnt above already drained this
                // slot's canary reset (issued step s-2); per-lane in-order
                if (s+1 < TT) {
                    const float* ah = &hb1[((s+1)&3)*HH + b2];
                    const float* ac = &hb1[((s+3)&3)*HH + b2];
                    f2 can = {CANARY, CANARY};
                    asm volatile("global_store_dwordx2 %0, %1, off sc0 sc1"
                                 :: "v"(ah), "v"(pack) : "memory");
                    asm volatile("global_store_dwordx2 %0, %1, off sc0 sc1"
                                 :: "v"(ac), "v"(can) : "memory");
                }
                *(f2*)&hcat[(size_t)(TT-1-s)*1024 + 1*HH + b2] = pack;
            }
        }

        if (s+1 < TT) {
            if (k8 == 0) {                       // prefetch next xv, both dirs
                xv0 = xw0[(size_t)(s+1)*G4 + row];
                xv1 = xw1[(size_t)(TT-2-s)*G4 + row];
            }

            const int slot = (s+1) & 3;
            if (v < 4) {                         // waves 0-1: dir0; 2-3: dir1
                const int d   = v >> 1;
                const int pv  = v & 1;
                const int fbase = (pv*64 + l)*4; // 4 floats of [0,512)
                const float* ap = (d ? hb1 : hb0) + slot*HH + fbase;
                f4 hv; int guard = 0;
                for (;;) {
                    asm volatile("global_load_dwordx4 %0, %1, off sc0 sc1\n\t"
                                 "s_waitcnt vmcnt(0)"
                                 : "=v"(hv) : "v"(ap) : "memory");
                    if (hv.x != CANARY && hv.y != CANARY &&
                        hv.z != CANARY && hv.w != CANARY) break;
                    if (++guard > (1<<17)) break;          // fail-visible
                    __builtin_amdgcn_s_sleep(1);
                }
                *(f4*)&hsh[(s+1)&1][d][(fbase>>6)*68 + (fbase&63)] = hv;
            }
            __syncthreads();                     // restage complete
        }
    }
}

// ---------------------------------------------------------------------------
// K3: frames[t][j] = dot(hcat[t], Wout[j]) + bout[j]; one block per t.
// ---------------------------------------------------------------------------
__global__ __launch_bounds__(64) void k_frames(
    const float* __restrict__ hcat, const float* __restrict__ Wout,
    const float* __restrict__ bout, float* __restrict__ frames)
{
    const int t = blockIdx.x, tid = threadIdx.x;
    __shared__ float hrow[1024];
    const float4* src  = (const float4*)&hcat[(size_t)t*1024];
    float4* dst4 = (float4*)hrow;
    #pragma unroll
    for (int u = 0; u < 4; u++) dst4[u*64 + tid] = src[u*64 + tid];
    __syncthreads();
    if (tid < NTAGS) {
        float acc = bout[tid];
        const float4* wr = (const float4*)&Wout[(size_t)tid*1024];
        #pragma unroll 16
        for (int e = 0; e < 256; e++) {
            float4 wv = wr[e];
            float4 hv = dst4[e];
            acc += wv.x*hv.x + wv.y*hv.y + wv.z*hv.z + wv.w*hv.w;
        }
        frames[t*NTAGS + tid] = acc;
    }
}

// ---------------------------------------------------------------------------
// K4: Viterbi scan (1 WG, 4-way i-split + LDS reduce, frames double-buffered)
// + backtrace chased through LDS in 256-row chunks.
// First-max tie-breaking matches jnp.argmax (ascending i, strict >).
// ---------------------------------------------------------------------------
#define CH 256
__global__ __launch_bounds__(256) void k_viterbi(
    const float* __restrict__ frames, const float* __restrict__ trans,
    const int* __restrict__ startp, const int* __restrict__ endp,
    unsigned char* __restrict__ bp, float* __restrict__ out)
{
    const int tid = threadIdx.x;
    const int grp = tid / NTAGS;      // 0..3 compute, 4 = prefetch, rest idle
    const int j   = tid % NTAGS;
    __shared__ float alpha[2][NTAGS];
    __shared__ float red[4][NTAGS];
    __shared__ int   redarg[4][NTAGS];
    __shared__ float frbuf[2][NTAGS];
    __shared__ __align__(16) unsigned char bps[CH*NTAGS];   // 12 KB
    __shared__ int s_tag;

    float tr[12];
    if (grp < 4) {
        #pragma unroll
        for (int u = 0; u < 12; u++) tr[u] = trans[j*NTAGS + grp*12 + u]; // transitions[j][i]
    }
    const int start_tag = *startp;
    if (tid < NTAGS) alpha[0][tid] = (tid == start_tag) ? 0.f : -10000.f;
    const bool is_pf = (tid >= 192 && tid < 192 + NTAGS);
    if (is_pf) frbuf[0][tid-192] = frames[tid-192];
    __syncthreads();

    for (int t = 0; t < TT; t++) {
        float fpre = 0.f;
        if (is_pf && t+1 < TT) fpre = frames[(t+1)*NTAGS + (tid-192)];
        if (grp < 4) {
            float best = -3.0e38f; int barg = 0;
            #pragma unroll
            for (int u = 0; u < 12; u++) {
                float sv = alpha[t&1][grp*12+u] + tr[u];
                if (sv > best) { best = sv; barg = grp*12+u; }
            }
            red[grp][j] = best; redarg[grp][j] = barg;
        }
        __syncthreads();
        if (tid < NTAGS) {
            float b = red[0][tid]; int a = redarg[0][tid];
            #pragma unroll
            for (int g2 = 1; g2 < 4; g2++) {
                float v = red[g2][tid];
                if (v > b) { b = v; a = redarg[g2][tid]; }
            }
            bp[t*NTAGS + tid] = (unsigned char)a;
            alpha[(t+1)&1][tid] = b + frbuf[t&1][tid];
        }
        __syncthreads();
        if (is_pf && t+1 < TT) frbuf[(t+1)&1][tid-192] = fpre;
    }

    if (tid == 0) {
        const int end_tag = *endp;
        float best = -3.0e38f; int bl = 0;
        for (int j2 = 0; j2 < NTAGS; j2++) {
            float v = alpha[0][j2] + trans[end_tag*NTAGS + j2];  // TT even -> parity 0
            if (v > best) { best = v; bl = j2; }
        }
        out[0] = best;
        out[1 + TT - 1] = (float)bl;
        s_tag = bl;
    }
    __syncthreads();

    // chunked backtrace: t = TT-1 .. 1, chunks descending
    for (int base = TT - CH; base >= 0; base -= CH) {
        {   // parallel load of rows [base, base+CH) into LDS (48 B each)
            const float4* srcr = (const float4*)&bp[(size_t)(base + tid)*NTAGS];
            float4* dstr = (float4*)&bps[tid*NTAGS];
            dstr[0] = srcr[0]; dstr[1] = srcr[1]; dstr[2] = srcr[2];
        }
        __syncthreads();
        if (tid == 0) {
            int tag = s_tag;
            const int thi = base + CH - 1;
            const int tlo = (base == 0) ? 1 : base;
            for (int t = thi; t >= tlo; t--) {
                tag = bps[(t - base)*NTAGS + tag];
                out[t] = (float)tag;
            }
            s_tag = tag;
        }
        __syncthreads();
    }
}

extern "C" void kernel_launch(void* const* d_in, const int* in_sizes, int n_in,
                              void* d_out, int out_size, void* d_ws, size_t ws_size,
                              hipStream_t stream)
{
    const int*   words = (const int*)  d_in[0];
    const float* embed = (const float*)d_in[1];
    const float* WihF  = (const float*)d_in[2];
    const float* WhhF  = (const float*)d_in[3];
    const float* bihF  = (const float*)d_in[4];
    const float* bhhF  = (const float*)d_in[5];
    const float* WihB  = (const float*)d_in[6];
    const float* WhhB  = (const float*)d_in[7];
    const float* bihB  = (const float*)d_in[8];
    const float* bhhB  = (const float*)d_in[9];
    const float* Wout  = (const float*)d_in[10];
    const float* bout  = (const float*)d_in[11];
    const float* trans = (const float*)d_in[12];
    const float* h0    = (const float*)d_in[13];
    const float* c0    = (const float*)d_in[14];
    const int*   startp= (const int*)  d_in[15];
    const int*   endp  = (const int*)  d_in[16];

    char* ws = (char*)d_ws;
    float* xw   = (float*)(ws + OFF_XW);
    float* hcat = (float*)(ws + OFF_HCAT);
    float* frm  = (float*)(ws + OFF_FRM);
    float* hbuf = (float*)(ws + OFF_HBUF);
    unsigned char* bp = (unsigned char*)(ws + OFF_BP);

    dim3 g1(32, 32, 2);
    k_xw<<<g1, 256, 0, stream>>>(words, embed, WihF, WihB, bihF, bhhF,
                                 bihB, bhhB, xw, hbuf);
    k_lstm<<<dim3(32), 512, 0, stream>>>(WhhF, WhhB, h0, c0, xw, hbuf, hcat);
    k_frames<<<dim3(TT), 64, 0, stream>>>(hcat, Wout, bout, frm);
    k_viterbi<<<dim3(1), 256, 0, stream>>>(frm, trans, startp, endp, bp, (float*)d_out);
}

// Round 8
// 8649.886 us; speedup vs baseline: 1.0019x; 1.0019x over previous
//
#include <hip/hip_runtime.h>

#define TT 2048
#define HH 512
#define EE 512
#define NTAGS 48
#define G4 2048   // 4*HH
#define CANARY 1.0e30f

typedef float f4 __attribute__((ext_vector_type(4)));
typedef float f2 __attribute__((ext_vector_type(2)));

// workspace byte offsets
#define OFF_XW    0ULL                                      // [2][TT][G4] f32 = 32 MB
#define OFF_HCAT  (OFF_XW   + 2ULL*TT*G4*4ULL)              // [TT][1024] f32 = 8 MB
#define OFF_FRM   (OFF_HCAT + (unsigned long long)TT*1024ULL*4ULL) // [TT][48] f32
#define OFF_HBUF  (OFF_FRM  + (unsigned long long)TT*NTAGS*4ULL)   // [2][4][HH] f32 (canary slots)
#define OFF_BP    (OFF_HBUF + 2ULL*4ULL*HH*4ULL)            // [TT][48] u8

// ---------------------------------------------------------------------------
// K1: xW[dir][t][r] = sum_e embed[words[t]][e]*Wih[dir][r][e] + bih[r]+bhh[r]
// 64x64 tile, 256 threads, 4x4 micro-tile, K-chunk 32. Also canary-fills the
// LSTM h exchange slots.
// ---------------------------------------------------------------------------
__global__ __launch_bounds__(256) void k_xw(
    const int* __restrict__ words, const float* __restrict__ embed,
    const float* __restrict__ WihF, const float* __restrict__ WihB,
    const float* __restrict__ bihF, const float* __restrict__ bhhF,
    const float* __restrict__ bihB, const float* __restrict__ bhhB,
    float* __restrict__ xw, float* __restrict__ hbuf)
{
    const int tid = threadIdx.x;
    const int bx = blockIdx.x, by = blockIdx.y, dir = blockIdx.z;

    if (bx == 0 && by == 0) {                   // one block per dir: canary fill
        for (int j = tid; j < 4*HH; j += 256)
            hbuf[dir*4*HH + j] = CANARY;
    }

    const float* Wih = dir ? WihB : WihF;
    const float* bi  = dir ? bihB : bihF;
    const float* bh  = dir ? bhhB : bhhF;

    __shared__ float sa[32][64];
    __shared__ float sb[32][64];
    __shared__ int   wds[64];
    if (tid < 64) wds[tid] = words[by*64 + tid];
    const int tx = tid & 15, ty = tid >> 4;
    float acc[4][4] = {};
    __syncthreads();

    for (int k0 = 0; k0 < EE; k0 += 32) {
        #pragma unroll
        for (int u = 0; u < 2; u++) {
            int idx = tid*2 + u;            // 0..511
            int row = idx >> 3, kq = idx & 7;
            float4 av = *(const float4*)&embed[(size_t)wds[row]*EE + k0 + kq*4];
            float4 bv = *(const float4*)&Wih[(size_t)(bx*64 + row)*EE + k0 + kq*4];
            sa[kq*4+0][row] = av.x; sa[kq*4+1][row] = av.y;
            sa[kq*4+2][row] = av.z; sa[kq*4+3][row] = av.w;
            sb[kq*4+0][row] = bv.x; sb[kq*4+1][row] = bv.y;
            sb[kq*4+2][row] = bv.z; sb[kq*4+3][row] = bv.w;
        }
        __syncthreads();
        #pragma unroll
        for (int k = 0; k < 32; k++) {
            float4 a = *(const float4*)&sa[k][ty*4];
            float4 b = *(const float4*)&sb[k][tx*4];
            acc[0][0] += a.x*b.x; acc[0][1] += a.x*b.y; acc[0][2] += a.x*b.z; acc[0][3] += a.x*b.w;
            acc[1][0] += a.y*b.x; acc[1][1] += a.y*b.y; acc[1][2] += a.y*b.z; acc[1][3] += a.y*b.w;
            acc[2][0] += a.z*b.x; acc[2][1] += a.z*b.y; acc[2][2] += a.z*b.z; acc[2][3] += a.z*b.w;
            acc[3][0] += a.w*b.x; acc[3][1] += a.w*b.y; acc[3][2] += a.w*b.z; acc[3][3] += a.w*b.w;
        }
        __syncthreads();
    }

    float* outp = xw + (size_t)dir*TT*G4;
    const int rbase = bx*64 + tx*4;
    float4 bi4 = *(const float4*)&bi[rbase];
    float4 bh4 = *(const float4*)&bh[rbase];
    float4 bias = make_float4(bi4.x+bh4.x, bi4.y+bh4.y, bi4.z+bh4.z, bi4.w+bh4.w);
    #pragma unroll
    for (int i = 0; i < 4; i++) {
        int t = by*64 + ty*4 + i;
        float4 v = make_float4(acc[i][0]+bias.x, acc[i][1]+bias.y,
                               acc[i][2]+bias.z, acc[i][3]+bias.w);
        *(float4*)&outp[(size_t)t*G4 + rbase] = v;
    }
}

// ---------------------------------------------------------------------------
// K2: Bi-LSTM recurrence, both directions interleaved per WG; h exchange via
// AGENT-scope (sc1-only -> LLC, NOT sc0sc1/HBM) canary-coded 4-slot buffer.
// 32 WGs x 512 thr; WG w owns h-outputs [16w,16w+16) of both dirs.
// Per step: dot0 -> gates0 -> store h0 -> dot1 -> gates1 -> store h1 ->
// xv prefetch -> waves0-1 poll dir0 / waves2-3 poll dir1 (dwordx4 sc1,
// sleep(1)) -> restage LDS -> one barrier. Single per-step vmcnt(0) before
// dir0 stores drains both dirs' 2-step-old canary resets (per-lane in-order).
// ---------------------------------------------------------------------------
__global__ __launch_bounds__(512, 2) void k_lstm(
    const float* __restrict__ WhhF, const float* __restrict__ WhhB,
    const float* __restrict__ h0, const float* __restrict__ cinit,
    const float* __restrict__ xw,
    float* __restrict__ hbuf, float* __restrict__ hcat)
{
    const int w   = blockIdx.x;          // 0..31
    const int tid = threadIdx.x;
    const int v   = tid >> 6;            // wave 0..7
    const int l   = tid & 63;
    const int o   = l >> 5;              // 0..1: which h-output of the wave
    const int g   = (l >> 3) & 3;        // gate 0:i 1:f 2:g 3:o
    const int k8  = l & 7;               // K-octant (64 floats)
    const int hidx = w*16 + v*2 + o;     // global h index [0,512)
    const int row  = g*HH + hidx;        // Whh row

    float* hb0 = hbuf;                   // dir0 [4][HH]
    float* hb1 = hbuf + 4*HH;            // dir1
    const float* xw0 = xw;
    const float* xw1 = xw + (size_t)TT*G4;

    // weights, both dirs: 16 float4 each (128 VGPR), keep-live
    float4 w0[16], w1[16];
    {
        const float4* p0 = (const float4*)&WhhF[(size_t)row*HH + k8*64];
        const float4* p1 = (const float4*)&WhhB[(size_t)row*HH + k8*64];
        #pragma unroll
        for (int t = 0; t < 16; t++) { w0[t] = p0[t]; w1[t] = p1[t]; }
        #pragma unroll
        for (int t = 0; t < 16; t++) {
            asm volatile("" : "+v"(w0[t].x), "+v"(w0[t].y), "+v"(w0[t].z), "+v"(w0[t].w));
            asm volatile("" : "+v"(w1[t].x), "+v"(w1[t].y), "+v"(w1[t].z), "+v"(w1[t].w));
        }
    }
    float c0r = cinit[0*HH + hidx];      // redundant across the 32 lanes of o
    float c1r = cinit[1*HH + hidx];

    // [buf][dir][8 chunks x 68 floats]
    __shared__ __align__(16) float hsh[2][2][8*68];
    {
        int ch = tid >> 6, of = tid & 63;
        hsh[0][0][ch*68 + of] = h0[0*HH + tid];
        hsh[0][1][ch*68 + of] = h0[1*HH + tid];
    }
    __syncthreads();

    float xv0 = 0.f, xv1 = 0.f;
    if (k8 == 0) {
        xv0 = xw0[(size_t)0*G4 + row];            // dir0 t=0
        xv1 = xw1[(size_t)(TT-1)*G4 + row];       // dir1 t=TT-1
    }

    const int ob = l & 32;               // o-group base lane

    for (int s = 0; s < TT; s++) {
        // ================= dir 0 =================
        float h0n;
        {
            const float* hc = &hsh[s & 1][0][k8*68];
            float p0=0.f,p1=0.f,p2=0.f,p3=0.f;
            #pragma unroll
            for (int t = 0; t < 16; t++) {
                float4 hv = *(const float4*)&hc[4*t];
                p0 += w0[t].x*hv.x; p1 += w0[t].y*hv.y;
                p2 += w0[t].z*hv.z; p3 += w0[t].w*hv.w;
            }
            float p = (p0+p1)+(p2+p3);
            if (k8 == 0) p += xv0;
            p += __shfl_xor(p, 1); p += __shfl_xor(p, 2); p += __shfl_xor(p, 4);
            float gi = __shfl(p, ob+0),  gf = __shfl(p, ob+8);
            float gg = __shfl(p, ob+16), go = __shfl(p, ob+24);
            float i_ = 1.f/(1.f + expf(-gi));
            float f_ = 1.f/(1.f + expf(-gf));
            float g_ = tanhf(gg);
            float o_ = 1.f/(1.f + expf(-go));
            c0r = f_*c0r + i_*g_;
            h0n = o_*tanhf(c0r);
        }
        {   // producer: lane 0 per wave, 2 floats (o=0,1)
            float ha = __shfl(h0n, 0), hbv = __shfl(h0n, 32);
            if (l == 0) {
                f2 pack = {ha, hbv};
                const int b2 = w*16 + v*2;
                // single per-step ordering point: drains BOTH dirs' canary
                // resets issued at step s-2 (same lane) before any h-store
                asm volatile("s_waitcnt vmcnt(0)" ::: "memory");
                if (s+1 < TT) {
                    const float* ah = &hb0[((s+1)&3)*HH + b2];
                    const float* ac = &hb0[((s+3)&3)*HH + b2];
                    f2 can = {CANARY, CANARY};
                    asm volatile("global_store_dwordx2 %0, %1, off sc1"
                                 :: "v"(ah), "v"(pack) : "memory");
                    asm volatile("global_store_dwordx2 %0, %1, off sc1"
                                 :: "v"(ac), "v"(can) : "memory");
                }
                *(f2*)&hcat[(size_t)s*1024 + 0*HH + b2] = pack;   // time0 = s
            }
        }

        // ================= dir 1 ================= (hides dir0 store latency)
        float h1n;
        {
            const float* hc = &hsh[s & 1][1][k8*68];
            float p0=0.f,p1=0.f,p2=0.f,p3=0.f;
            #pragma unroll
            for (int t = 0; t < 16; t++) {
                float4 hv = *(const float4*)&hc[4*t];
                p0 += w1[t].x*hv.x; p1 += w1[t].y*hv.y;
                p2 += w1[t].z*hv.z; p3 += w1[t].w*hv.w;
            }
            float p = (p0+p1)+(p2+p3);
            if (k8 == 0) p += xv1;
            p += __shfl_xor(p, 1); p += __shfl_xor(p, 2); p += __shfl_xor(p, 4);
            float gi = __shfl(p, ob+0),  gf = __shfl(p, ob+8);
            float gg = __shfl(p, ob+16), go = __shfl(p, ob+24);
            float i_ = 1.f/(1.f + expf(-gi));
            float f_ = 1.f/(1.f + expf(-gf));
            float g_ = tanhf(gg);
            float o_ = 1.f/(1.f + expf(-go));
            c1r = f_*c1r + i_*g_;
            h1n = o_*tanhf(c1r);
        }
        {
            float ha = __shfl(h1n, 0), hbv = __shfl(h1n, 32);
            if (l == 0) {
                f2 pack = {ha, hbv};
                const int b2 = w*16 + v*2;
                // no wait needed: step-s vmcnt above already drained this
                // slot's canary reset (issued step s-2); per-lane in-order
                if (s+1 < TT) {
                    const float* ah = &hb1[((s+1)&3)*HH + b2];
                    const float* ac = &hb1[((s+3)&3)*HH + b2];
                    f2 can = {CANARY, CANARY};
                    asm volatile("global_store_dwordx2 %0, %1, off sc1"
                                 :: "v"(ah), "v"(pack) : "memory");
                    asm volatile("global_store_dwordx2 %0, %1, off sc1"
                                 :: "v"(ac), "v"(can) : "memory");
                }
                *(f2*)&hcat[(size_t)(TT-1-s)*1024 + 1*HH + b2] = pack;
            }
        }

        if (s+1 < TT) {
            if (k8 == 0) {                       // prefetch next xv, both dirs
                xv0 = xw0[(size_t)(s+1)*G4 + row];
                xv1 = xw1[(size_t)(TT-2-s)*G4 + row];
            }

            const int slot = (s+1) & 3;
            if (v < 4) {                         // waves 0-1: dir0; 2-3: dir1
                const int d   = v >> 1;
                const int pv  = v & 1;
                const int fbase = (pv*64 + l)*4; // 4 floats of [0,512)
                const float* ap = (d ? hb1 : hb0) + slot*HH + fbase;
                f4 hv; int guard = 0;
                for (;;) {
                    asm volatile("global_load_dwordx4 %0, %1, off sc1\n\t"
                                 "s_waitcnt vmcnt(0)"
                                 : "=v"(hv) : "v"(ap) : "memory");
                    if (hv.x != CANARY && hv.y != CANARY &&
                        hv.z != CANARY && hv.w != CANARY) break;
                    if (++guard > (1<<15)) break;          // fail-visible
                    __builtin_amdgcn_s_sleep(1);
                }
                *(f4*)&hsh[(s+1)&1][d][(fbase>>6)*68 + (fbase&63)] = hv;
            }
            __syncthreads();                     // restage complete
        }
    }
}

// ---------------------------------------------------------------------------
// K3: frames[t][j] = dot(hcat[t], Wout[j]) + bout[j]; one block per t.
// ---------------------------------------------------------------------------
__global__ __launch_bounds__(64) void k_frames(
    const float* __restrict__ hcat, const float* __restrict__ Wout,
    const float* __restrict__ bout, float* __restrict__ frames)
{
    const int t = blockIdx.x, tid = threadIdx.x;
    __shared__ float hrow[1024];
    const float4* src  = (const float4*)&hcat[(size_t)t*1024];
    float4* dst4 = (float4*)hrow;
    #pragma unroll
    for (int u = 0; u < 4; u++) dst4[u*64 + tid] = src[u*64 + tid];
    __syncthreads();
    if (tid < NTAGS) {
        float acc = bout[tid];
        const float4* wr = (const float4*)&Wout[(size_t)tid*1024];
        #pragma unroll 16
        for (int e = 0; e < 256; e++) {
            float4 wv = wr[e];
            float4 hv = dst4[e];
            acc += wv.x*hv.x + wv.y*hv.y + wv.z*hv.z + wv.w*hv.w;
        }
        frames[t*NTAGS + tid] = acc;
    }
}

// ---------------------------------------------------------------------------
// K4: Viterbi scan (1 WG, 4-way i-split + LDS reduce, frames double-buffered)
// + backtrace chased through LDS in 256-row chunks.
// First-max tie-breaking matches jnp.argmax (ascending i, strict >).
// ---------------------------------------------------------------------------
#define CH 256
__global__ __launch_bounds__(256) void k_viterbi(
    const float* __restrict__ frames, const float* __restrict__ trans,
    const int* __restrict__ startp, const int* __restrict__ endp,
    unsigned char* __restrict__ bp, float* __restrict__ out)
{
    const int tid = threadIdx.x;
    const int grp = tid / NTAGS;      // 0..3 compute, 4 = prefetch, rest idle
    const int j   = tid % NTAGS;
    __shared__ float alpha[2][NTAGS];
    __shared__ float red[4][NTAGS];
    __shared__ int   redarg[4][NTAGS];
    __shared__ float frbuf[2][NTAGS];
    __shared__ __align__(16) unsigned char bps[CH*NTAGS];   // 12 KB
    __shared__ int s_tag;

    float tr[12];
    if (grp < 4) {
        #pragma unroll
        for (int u = 0; u < 12; u++) tr[u] = trans[j*NTAGS + grp*12 + u]; // transitions[j][i]
    }
    const int start_tag = *startp;
    if (tid < NTAGS) alpha[0][tid] = (tid == start_tag) ? 0.f : -10000.f;
    const bool is_pf = (tid >= 192 && tid < 192 + NTAGS);
    if (is_pf) frbuf[0][tid-192] = frames[tid-192];
    __syncthreads();

    for (int t = 0; t < TT; t++) {
        float fpre = 0.f;
        if (is_pf && t+1 < TT) fpre = frames[(t+1)*NTAGS + (tid-192)];
        if (grp < 4) {
            float best = -3.0e38f; int barg = 0;
            #pragma unroll
            for (int u = 0; u < 12; u++) {
                float sv = alpha[t&1][grp*12+u] + tr[u];
                if (sv > best) { best = sv; barg = grp*12+u; }
            }
            red[grp][j] = best; redarg[grp][j] = barg;
        }
        __syncthreads();
        if (tid < NTAGS) {
            float b = red[0][tid]; int a = redarg[0][tid];
            #pragma unroll
            for (int g2 = 1; g2 < 4; g2++) {
                float v = red[g2][tid];
                if (v > b) { b = v; a = redarg[g2][tid]; }
            }
            bp[t*NTAGS + tid] = (unsigned char)a;
            alpha[(t+1)&1][tid] = b + frbuf[t&1][tid];
        }
        __syncthreads();
        if (is_pf && t+1 < TT) frbuf[(t+1)&1][tid-192] = fpre;
    }

    if (tid == 0) {
        const int end_tag = *endp;
        float best = -3.0e38f; int bl = 0;
        for (int j2 = 0; j2 < NTAGS; j2++) {
            float v = alpha[0][j2] + trans[end_tag*NTAGS + j2];  // TT even -> parity 0
            if (v > best) { best = v; bl = j2; }
        }
        out[0] = best;
        out[1 + TT - 1] = (float)bl;
        s_tag = bl;
    }
    __syncthreads();

    // chunked backtrace: t = TT-1 .. 1, chunks descending
    for (int base = TT - CH; base >= 0; base -= CH) {
        {   // parallel load of rows [base, base+CH) into LDS (48 B each)
            const float4* srcr = (const float4*)&bp[(size_t)(base + tid)*NTAGS];
            float4* dstr = (float4*)&bps[tid*NTAGS];
            dstr[0] = srcr[0]; dstr[1] = srcr[1]; dstr[2] = srcr[2];
        }
        __syncthreads();
        if (tid == 0) {
            int tag = s_tag;
            const int thi = base + CH - 1;
            const int tlo = (base == 0) ? 1 : base;
            for (int t = thi; t >= tlo; t--) {
                tag = bps[(t - base)*NTAGS + tag];
                out[t] = (float)tag;
            }
            s_tag = tag;
        }
        __syncthreads();
    }
}

extern "C" void kernel_launch(void* const* d_in, const int* in_sizes, int n_in,
                              void* d_out, int out_size, void* d_ws, size_t ws_size,
                              hipStream_t stream)
{
    const int*   words = (const int*)  d_in[0];
    const float* embed = (const float*)d_in[1];
    const float* WihF  = (const float*)d_in[2];
    const float* WhhF  = (const float*)d_in[3];
    const float* bihF  = (const float*)d_in[4];
    const float* bhhF  = (const float*)d_in[5];
    const float* WihB  = (const float*)d_in[6];
    const float* WhhB  = (const float*)d_in[7];
    const float* bihB  = (const float*)d_in[8];
    const float* bhhB  = (const float*)d_in[9];
    const float* Wout  = (const float*)d_in[10];
    const float* bout  = (const float*)d_in[11];
    const float* trans = (const float*)d_in[12];
    const float* h0    = (const float*)d_in[13];
    const float* c0    = (const float*)d_in[14];
    const int*   startp= (const int*)  d_in[15];
    const int*   endp  = (const int*)  d_in[16];

    char* ws = (char*)d_ws;
    float* xw   = (float*)(ws + OFF_XW);
    float* hcat = (float*)(ws + OFF_HCAT);
    float* frm  = (float*)(ws + OFF_FRM);
    float* hbuf = (float*)(ws + OFF_HBUF);
    unsigned char* bp = (unsigned char*)(ws + OFF_BP);

    dim3 g1(32, 32, 2);
    k_xw<<<g1, 256, 0, stream>>>(words, embed, WihF, WihB, bihF, bhhF,
                                 bihB, bhhB, xw, hbuf);
    k_lstm<<<dim3(32), 512, 0, stream>>>(WhhF, WhhB, h0, c0, xw, hbuf, hcat);
    k_frames<<<dim3(TT), 64, 0, stream>>>(hcat, Wout, bout, frm);
    k_viterbi<<<dim3(1), 256, 0, stream>>>(frm, trans, startp, endp, bp, (float*)d_out);
}

// Round 9
// 6553.569 us; speedup vs baseline: 1.3224x; 1.3199x over previous
//
#include <hip/hip_runtime.h>

#define TT 2048
#define HH 512
#define EE 512
#define NTAGS 48
#define G4 2048   // 4*HH
#define NWG 16    // workgroups per direction in the LSTM kernel
#define CANARY 1.0e30f

// workspace byte offsets
#define OFF_XW    0ULL                                      // [2][TT][G4] f32 = 32 MB
#define OFF_HCAT  (OFF_XW   + 2ULL*TT*G4*4ULL)              // [TT][1024] f32 = 8 MB
#define OFF_FRM   (OFF_HCAT + (unsigned long long)TT*1024ULL*4ULL) // [TT][48] f32
#define OFF_HBUF  (OFF_FRM  + (unsigned long long)TT*NTAGS*4ULL)   // [2][4][HH] f32 (canary slots)
#define OFF_BP    (OFF_HBUF + 2ULL*4ULL*HH*4ULL)            // [TT][48] u8

// ---------------------------------------------------------------------------
// K1: xW[dir][t][r] = sum_e embed[words[t]][e]*Wih[dir][r][e] + bih[r]+bhh[r]
// 64x64 tile, 256 threads, 4x4 micro-tile, K-chunk 32. Also canary-fills the
// LSTM h exchange slots.
// ---------------------------------------------------------------------------
__global__ __launch_bounds__(256) void k_xw(
    const int* __restrict__ words, const float* __restrict__ embed,
    const float* __restrict__ WihF, const float* __restrict__ WihB,
    const float* __restrict__ bihF, const float* __restrict__ bhhF,
    const float* __restrict__ bihB, const float* __restrict__ bhhB,
    float* __restrict__ xw, float* __restrict__ hbuf)
{
    const int tid = threadIdx.x;
    const int bx = blockIdx.x, by = blockIdx.y, dir = blockIdx.z;

    if (bx == 0 && by == 0) {                   // one block per dir: canary fill
        for (int j = tid; j < 4*HH; j += 256)
            hbuf[dir*4*HH + j] = CANARY;
    }

    const float* Wih = dir ? WihB : WihF;
    const float* bi  = dir ? bihB : bihF;
    const float* bh  = dir ? bhhB : bhhF;

    __shared__ float sa[32][64];
    __shared__ float sb[32][64];
    __shared__ int   wds[64];
    if (tid < 64) wds[tid] = words[by*64 + tid];
    const int tx = tid & 15, ty = tid >> 4;
    float acc[4][4] = {};
    __syncthreads();

    for (int k0 = 0; k0 < EE; k0 += 32) {
        #pragma unroll
        for (int u = 0; u < 2; u++) {
            int idx = tid*2 + u;            // 0..511
            int row = idx >> 3, kq = idx & 7;
            float4 av = *(const float4*)&embed[(size_t)wds[row]*EE + k0 + kq*4];
            float4 bv = *(const float4*)&Wih[(size_t)(bx*64 + row)*EE + k0 + kq*4];
            sa[kq*4+0][row] = av.x; sa[kq*4+1][row] = av.y;
            sa[kq*4+2][row] = av.z; sa[kq*4+3][row] = av.w;
            sb[kq*4+0][row] = bv.x; sb[kq*4+1][row] = bv.y;
            sb[kq*4+2][row] = bv.z; sb[kq*4+3][row] = bv.w;
        }
        __syncthreads();
        #pragma unroll
        for (int k = 0; k < 32; k++) {
            float4 a = *(const float4*)&sa[k][ty*4];
            float4 b = *(const float4*)&sb[k][tx*4];
            acc[0][0] += a.x*b.x; acc[0][1] += a.x*b.y; acc[0][2] += a.x*b.z; acc[0][3] += a.x*b.w;
            acc[1][0] += a.y*b.x; acc[1][1] += a.y*b.y; acc[1][2] += a.y*b.z; acc[1][3] += a.y*b.w;
            acc[2][0] += a.z*b.x; acc[2][1] += a.z*b.y; acc[2][2] += a.z*b.z; acc[2][3] += a.z*b.w;
            acc[3][0] += a.w*b.x; acc[3][1] += a.w*b.y; acc[3][2] += a.w*b.z; acc[3][3] += a.w*b.w;
        }
        __syncthreads();
    }

    float* outp = xw + (size_t)dir*TT*G4;
    const int rbase = bx*64 + tx*4;
    float4 bi4 = *(const float4*)&bi[rbase];
    float4 bh4 = *(const float4*)&bh[rbase];
    float4 bias = make_float4(bi4.x+bh4.x, bi4.y+bh4.y, bi4.z+bh4.z, bi4.w+bh4.w);
    #pragma unroll
    for (int i = 0; i < 4; i++) {
        int t = by*64 + ty*4 + i;
        float4 v = make_float4(acc[i][0]+bias.x, acc[i][1]+bias.y,
                               acc[i][2]+bias.z, acc[i][3]+bias.w);
        *(float4*)&outp[(size_t)t*G4 + rbase] = v;
    }
}

// ---------------------------------------------------------------------------
// K2: Bi-LSTM recurrence = round-5 compute structure + round-3 poll
// discipline (the factorial completion; only delta vs round 5 is the
// s_sleep(2) backoff in the poll loops):
//  - 16-way K-split dot: thread owns one 32-float h chunk x all 4 gates
//  - float4 butterfly reduce over 16 lanes; activations distributed on
//    lanes 0-3; gathered by shfl; c/h redundant on all 16 lanes
//  - storer lane (k16==4): vmcnt(0) [drains 2-step-old canary reset], then
//    h store + canary-reset (relaxed agent atomics) + hcat fire-and-forget
//  - all other lanes poll OWN element with s_sleep(2) backoff (buddy lane
//    k16==5 also covers the storer's element); 1 barrier per step
// ---------------------------------------------------------------------------
__global__ __launch_bounds__(512, 2) void k_lstm(
    const float* __restrict__ WhhF, const float* __restrict__ WhhB,
    const float* __restrict__ h0, const float* __restrict__ c0,
    const float* __restrict__ xw,
    float* __restrict__ hbuf, float* __restrict__ hcat)
{
    const int bid = blockIdx.x;
    const int dir = bid >> 4;
    const int w   = bid & 15;
    const float* Whh = dir ? WhhB : WhhF;
    const float* xwD = xw + (size_t)dir*TT*G4;
    float* hb = hbuf + dir*4*HH;            // [slot][HH]

    const int tid  = threadIdx.x;
    const int v    = tid >> 6;              // wave 0..7
    const int l    = tid & 63;
    const int hi   = l >> 4;                // 0..3: wave's 4 h-outputs
    const int k16  = l & 15;                // K-chunk / role id
    const int hidx = w*32 + v*4 + hi;       // global h index [0,512)

    // weights: 4 gate-rows x this thread's 32-float K-chunk (128 VGPR)
    float4 wreg[4][8];
    #pragma unroll
    for (int g = 0; g < 4; g++) {
        const float4* wr = (const float4*)&Whh[(size_t)(g*HH + hidx)*HH + k16*32];
        #pragma unroll
        for (int t = 0; t < 8; t++) wreg[g][t] = wr[t];
    }
    #pragma unroll
    for (int g = 0; g < 4; g++)
        #pragma unroll
        for (int t = 0; t < 8; t++)
            asm volatile("" : "+v"(wreg[g][t].x), "+v"(wreg[g][t].y),
                              "+v"(wreg[g][t].z), "+v"(wreg[g][t].w));

    float c = c0[dir*HH + hidx];            // redundant across 16 lanes

    // chunk-padded h staging: chunk cc at float offset 36*cc (16B-aligned,
    // banks (4cc+4t)&31 -> only 2-way aliasing = free)
    __shared__ __align__(16) float hsh[2][16*36];

    hsh[0][(tid>>5)*36 + (tid&31)] = h0[dir*HH + tid];
    __syncthreads();

    float xv = 0.f;
    if (k16 < 4) xv = xwD[(size_t)(dir ? TT-1 : 0)*G4 + k16*HH + hidx];

    for (int s = 0; s < TT; s++) {
        // ---- dot over own chunk, 4 gates share the h loads ----
        const float* hc = &hsh[s & 1][k16*36];
        float4 p = make_float4(0.f, 0.f, 0.f, 0.f);
        #pragma unroll
        for (int t = 0; t < 8; t++) {
            float4 hv = *(const float4*)&hc[4*t];
            p.x += wreg[0][t].x*hv.x; p.x += wreg[0][t].y*hv.y;
            p.x += wreg[0][t].z*hv.z; p.x += wreg[0][t].w*hv.w;
            p.y += wreg[1][t].x*hv.x; p.y += wreg[1][t].y*hv.y;
            p.y += wreg[1][t].z*hv.z; p.y += wreg[1][t].w*hv.w;
            p.z += wreg[2][t].x*hv.x; p.z += wreg[2][t].y*hv.y;
            p.z += wreg[2][t].z*hv.z; p.z += wreg[2][t].w*hv.w;
            p.w += wreg[3][t].x*hv.x; p.w += wreg[3][t].y*hv.y;
            p.w += wreg[3][t].z*hv.z; p.w += wreg[3][t].w*hv.w;
        }
        // xv for gate g added exactly once (by lane k16==g)
        if (k16 == 0) p.x += xv;
        else if (k16 == 1) p.y += xv;
        else if (k16 == 2) p.z += xv;
        else if (k16 == 3) p.w += xv;

        // ---- 16-lane butterfly reduce (float4) ----
        #pragma unroll
        for (int m = 1; m < 16; m <<= 1) {
            p.x += __shfl_xor(p.x, m);
            p.y += __shfl_xor(p.y, m);
            p.z += __shfl_xor(p.z, m);
            p.w += __shfl_xor(p.w, m);
        }

        // ---- distributed activations on lanes 0..3 ----
        float act = 0.f;
        if (k16 < 4) {
            float sv = (k16 == 0) ? p.x : (k16 == 1) ? p.y : (k16 == 2) ? p.z : p.w;
            act = (k16 == 2) ? tanhf(sv) : 1.f/(1.f + expf(-sv));
        }
        const int base = l & ~15;
        float ai = __shfl(act, base + 0);
        float af = __shfl(act, base + 1);
        float ag = __shfl(act, base + 2);
        float ao = __shfl(act, base + 3);
        c = af*c + ai*ag;
        float hn = ao*tanhf(c);

        const int time = dir ? (TT-1-s) : s;
        if (k16 == 4) {                     // storer lane for this hi
            // R1 ordering: this lane's canary-reset from step s-2 (same slot
            // as the h-store below) must be complete first. ~2 steps old ->
            // near-free wait; vmcnt retires in order.
            asm volatile("s_waitcnt vmcnt(0)" ::: "memory");
            if (s+1 < TT) {
                __hip_atomic_store(&hb[((s+1)&3)*HH + hidx], hn,
                                   __ATOMIC_RELAXED, __HIP_MEMORY_SCOPE_AGENT);
                __hip_atomic_store(&hb[((s+3)&3)*HH + hidx], CANARY,
                                   __ATOMIC_RELAXED, __HIP_MEMORY_SCOPE_AGENT);
            }
            hcat[(size_t)time*1024 + dir*HH + hidx] = hn;   // fire-and-forget
        }

        if (s+1 < TT) {
            if (k16 < 4)                    // prefetch next xv
                xv = xwD[(size_t)(dir ? TT-2-s : s+1)*G4 + k16*HH + hidx];

            const int slot = (s+1) & 3;
            float* dst = &hsh[(s+1) & 1][0];
            if (k16 == 5) {
                // buddy: poll own element AND storer's (tid-1)
                const float* a0 = &hb[slot*HH + tid];
                const float* a1 = &hb[slot*HH + tid - 1];
                float h0v, h1v; int guard = 0;
                for (;;) {
                    h0v = __hip_atomic_load(a0, __ATOMIC_RELAXED, __HIP_MEMORY_SCOPE_AGENT);
                    h1v = __hip_atomic_load(a1, __ATOMIC_RELAXED, __HIP_MEMORY_SCOPE_AGENT);
                    if (h0v != CANARY && h1v != CANARY) break;
                    if (++guard > (1<<15)) break;          // fail-visible
                    __builtin_amdgcn_s_sleep(2);           // backoff (R3 discipline)
                }
                dst[(tid>>5)*36 + (tid&31)]       = h0v;
                dst[((tid-1)>>5)*36 + ((tid-1)&31)] = h1v;
            } else if (k16 != 4) {
                const float* a0 = &hb[slot*HH + tid];
                float h0v; int guard = 0;
                for (;;) {
                    h0v = __hip_atomic_load(a0, __ATOMIC_RELAXED, __HIP_MEMORY_SCOPE_AGENT);
                    if (h0v != CANARY) break;
                    if (++guard > (1<<15)) break;          // fail-visible
                    __builtin_amdgcn_s_sleep(2);           // backoff (R3 discipline)
                }
                dst[(tid>>5)*36 + (tid&31)] = h0v;
            }
            __syncthreads();                // restage complete
        }
    }
}

// ---------------------------------------------------------------------------
// K3: frames[t][j] = dot(hcat[t], Wout[j]) + bout[j]; one block per t.
// ---------------------------------------------------------------------------
__global__ __launch_bounds__(64) void k_frames(
    const float* __restrict__ hcat, const float* __restrict__ Wout,
    const float* __restrict__ bout, float* __restrict__ frames)
{
    const int t = blockIdx.x, tid = threadIdx.x;
    __shared__ float hrow[1024];
    const float4* src  = (const float4*)&hcat[(size_t)t*1024];
    float4* dst4 = (float4*)hrow;
    #pragma unroll
    for (int u = 0; u < 4; u++) dst4[u*64 + tid] = src[u*64 + tid];
    __syncthreads();
    if (tid < NTAGS) {
        float acc = bout[tid];
        const float4* wr = (const float4*)&Wout[(size_t)tid*1024];
        #pragma unroll 16
        for (int e = 0; e < 256; e++) {
            float4 wv = wr[e];
            float4 hv = dst4[e];
            acc += wv.x*hv.x + wv.y*hv.y + wv.z*hv.z + wv.w*hv.w;
        }
        frames[t*NTAGS + tid] = acc;
    }
}

// ---------------------------------------------------------------------------
// K4: Viterbi scan (1 WG, 4-way i-split + LDS reduce, frames double-buffered)
// + backtrace chased through LDS in 256-row chunks.
// First-max tie-breaking matches jnp.argmax (ascending i, strict >).
// ---------------------------------------------------------------------------
#define CH 256
__global__ __launch_bounds__(256) void k_viterbi(
    const float* __restrict__ frames, const float* __restrict__ trans,
    const int* __restrict__ startp, const int* __restrict__ endp,
    unsigned char* __restrict__ bp, float* __restrict__ out)
{
    const int tid = threadIdx.x;
    const int grp = tid / NTAGS;      // 0..3 compute, 4 = prefetch, rest idle
    const int j   = tid % NTAGS;
    __shared__ float alpha[2][NTAGS];
    __shared__ float red[4][NTAGS];
    __shared__ int   redarg[4][NTAGS];
    __shared__ float frbuf[2][NTAGS];
    __shared__ __align__(16) unsigned char bps[CH*NTAGS];   // 12 KB
    __shared__ int s_tag;

    float tr[12];
    if (grp < 4) {
        #pragma unroll
        for (int u = 0; u < 12; u++) tr[u] = trans[j*NTAGS + grp*12 + u]; // transitions[j][i]
    }
    const int start_tag = *startp;
    if (tid < NTAGS) alpha[0][tid] = (tid == start_tag) ? 0.f : -10000.f;
    const bool is_pf = (tid >= 192 && tid < 192 + NTAGS);
    if (is_pf) frbuf[0][tid-192] = frames[tid-192];
    __syncthreads();

    for (int t = 0; t < TT; t++) {
        float fpre = 0.f;
        if (is_pf && t+1 < TT) fpre = frames[(t+1)*NTAGS + (tid-192)];
        if (grp < 4) {
            float best = -3.0e38f; int barg = 0;
            #pragma unroll
            for (int u = 0; u < 12; u++) {
                float sv = alpha[t&1][grp*12+u] + tr[u];
                if (sv > best) { best = sv; barg = grp*12+u; }
            }
            red[grp][j] = best; redarg[grp][j] = barg;
        }
        __syncthreads();
        if (tid < NTAGS) {
            float b = red[0][tid]; int a = redarg[0][tid];
            #pragma unroll
            for (int g2 = 1; g2 < 4; g2++) {
                float v = red[g2][tid];
                if (v > b) { b = v; a = redarg[g2][tid]; }
            }
            bp[t*NTAGS + tid] = (unsigned char)a;
            alpha[(t+1)&1][tid] = b + frbuf[t&1][tid];
        }
        __syncthreads();
        if (is_pf && t+1 < TT) frbuf[(t+1)&1][tid-192] = fpre;
    }

    if (tid == 0) {
        const int end_tag = *endp;
        float best = -3.0e38f; int bl = 0;
        for (int j2 = 0; j2 < NTAGS; j2++) {
            float v = alpha[0][j2] + trans[end_tag*NTAGS + j2];  // TT even -> parity 0
            if (v > best) { best = v; bl = j2; }
        }
        out[0] = best;
        out[1 + TT - 1] = (float)bl;
        s_tag = bl;
    }
    __syncthreads();

    // chunked backtrace: t = TT-1 .. 1, chunks descending
    for (int base = TT - CH; base >= 0; base -= CH) {
        {   // parallel load of rows [base, base+CH) into LDS (48 B each)
            const float4* srcr = (const float4*)&bp[(size_t)(base + tid)*NTAGS];
            float4* dstr = (float4*)&bps[tid*NTAGS];
            dstr[0] = srcr[0]; dstr[1] = srcr[1]; dstr[2] = srcr[2];
        }
        __syncthreads();
        if (tid == 0) {
            int tag = s_tag;
            const int thi = base + CH - 1;
            const int tlo = (base == 0) ? 1 : base;
            for (int t = thi; t >= tlo; t--) {
                tag = bps[(t - base)*NTAGS + tag];
                out[t] = (float)tag;
            }
            s_tag = tag;
        }
        __syncthreads();
    }
}

extern "C" void kernel_launch(void* const* d_in, const int* in_sizes, int n_in,
                              void* d_out, int out_size, void* d_ws, size_t ws_size,
                              hipStream_t stream)
{
    const int*   words = (const int*)  d_in[0];
    const float* embed = (const float*)d_in[1];
    const float* WihF  = (const float*)d_in[2];
    const float* WhhF  = (const float*)d_in[3];
    const float* bihF  = (const float*)d_in[4];
    const float* bhhF  = (const float*)d_in[5];
    const float* WihB  = (const float*)d_in[6];
    const float* WhhB  = (const float*)d_in[7];
    const float* bihB  = (const float*)d_in[8];
    const float* bhhB  = (const float*)d_in[9];
    const float* Wout  = (const float*)d_in[10];
    const float* bout  = (const float*)d_in[11];
    const float* trans = (const float*)d_in[12];
    const float* h0    = (const float*)d_in[13];
    const float* c0    = (const float*)d_in[14];
    const int*   startp= (const int*)  d_in[15];
    const int*   endp  = (const int*)  d_in[16];

    char* ws = (char*)d_ws;
    float* xw   = (float*)(ws + OFF_XW);
    float* hcat = (float*)(ws + OFF_HCAT);
    float* frm  = (float*)(ws + OFF_FRM);
    float* hbuf = (float*)(ws + OFF_HBUF);
    unsigned char* bp = (unsigned char*)(ws + OFF_BP);

    dim3 g1(32, 32, 2);
    k_xw<<<g1, 256, 0, stream>>>(words, embed, WihF, WihB, bihF, bhhF,
                                 bihB, bhhB, xw, hbuf);
    k_lstm<<<dim3(2*NWG), 512, 0, stream>>>(WhhF, WhhB, h0, c0, xw, hbuf, hcat);
    k_frames<<<dim3(TT), 64, 0, stream>>>(hcat, Wout, bout, frm);
    k_viterbi<<<dim3(1), 256, 0, stream>>>(frm, trans, startp, endp, bp, (float*)d_out);
}

// Round 10
// 5405.929 us; speedup vs baseline: 1.6031x; 1.2123x over previous
//
#include <hip/hip_runtime.h>

#define TT 2048
#define HH 512
#define EE 512
#define NTAGS 48
#define G4 2048   // 4*HH
#define NWG 16    // workgroups per direction in the LSTM kernel
#define CANARY 1.0e30f

typedef float f4 __attribute__((ext_vector_type(4)));

// workspace byte offsets
#define OFF_XW    0ULL                                      // [2][TT][G4] f32 = 32 MB
#define OFF_HCAT  (OFF_XW   + 2ULL*TT*G4*4ULL)              // [TT][1024] f32 = 8 MB
#define OFF_FRM   (OFF_HCAT + (unsigned long long)TT*1024ULL*4ULL) // [TT][48] f32
#define OFF_HBUF  (OFF_FRM  + (unsigned long long)TT*NTAGS*4ULL)   // [2][4][HH] f32 (canary slots)
#define OFF_BP    (OFF_HBUF + 2ULL*4ULL*HH*4ULL)            // [TT][48] u8

// ---------------------------------------------------------------------------
// K1: xW[dir][t][r] = sum_e embed[words[t]][e]*Wih[dir][r][e] + bih[r]+bhh[r]
// 64x64 tile, 256 threads, 4x4 micro-tile, K-chunk 32. Also canary-fills the
// LSTM h exchange slots. (unchanged from round 3)
// ---------------------------------------------------------------------------
__global__ __launch_bounds__(256) void k_xw(
    const int* __restrict__ words, const float* __restrict__ embed,
    const float* __restrict__ WihF, const float* __restrict__ WihB,
    const float* __restrict__ bihF, const float* __restrict__ bhhF,
    const float* __restrict__ bihB, const float* __restrict__ bhhB,
    float* __restrict__ xw, float* __restrict__ hbuf)
{
    const int tid = threadIdx.x;
    const int bx = blockIdx.x, by = blockIdx.y, dir = blockIdx.z;

    if (bx == 0 && by == 0) {                   // one block per dir: canary fill
        for (int j = tid; j < 4*HH; j += 256)
            hbuf[dir*4*HH + j] = CANARY;
    }

    const float* Wih = dir ? WihB : WihF;
    const float* bi  = dir ? bihB : bihF;
    const float* bh  = dir ? bhhB : bhhF;

    __shared__ float sa[32][64];
    __shared__ float sb[32][64];
    __shared__ int   wds[64];
    if (tid < 64) wds[tid] = words[by*64 + tid];
    const int tx = tid & 15, ty = tid >> 4;
    float acc[4][4] = {};
    __syncthreads();

    for (int k0 = 0; k0 < EE; k0 += 32) {
        #pragma unroll
        for (int u = 0; u < 2; u++) {
            int idx = tid*2 + u;            // 0..511
            int row = idx >> 3, kq = idx & 7;
            float4 av = *(const float4*)&embed[(size_t)wds[row]*EE + k0 + kq*4];
            float4 bv = *(const float4*)&Wih[(size_t)(bx*64 + row)*EE + k0 + kq*4];
            sa[kq*4+0][row] = av.x; sa[kq*4+1][row] = av.y;
            sa[kq*4+2][row] = av.z; sa[kq*4+3][row] = av.w;
            sb[kq*4+0][row] = bv.x; sb[kq*4+1][row] = bv.y;
            sb[kq*4+2][row] = bv.z; sb[kq*4+3][row] = bv.w;
        }
        __syncthreads();
        #pragma unroll
        for (int k = 0; k < 32; k++) {
            float4 a = *(const float4*)&sa[k][ty*4];
            float4 b = *(const float4*)&sb[k][tx*4];
            acc[0][0] += a.x*b.x; acc[0][1] += a.x*b.y; acc[0][2] += a.x*b.z; acc[0][3] += a.x*b.w;
            acc[1][0] += a.y*b.x; acc[1][1] += a.y*b.y; acc[1][2] += a.y*b.z; acc[1][3] += a.y*b.w;
            acc[2][0] += a.z*b.x; acc[2][1] += a.z*b.y; acc[2][2] += a.z*b.z; acc[2][3] += a.z*b.w;
            acc[3][0] += a.w*b.x; acc[3][1] += a.w*b.y; acc[3][2] += a.w*b.z; acc[3][3] += a.w*b.w;
        }
        __syncthreads();
    }

    float* outp = xw + (size_t)dir*TT*G4;
    const int rbase = bx*64 + tx*4;
    float4 bi4 = *(const float4*)&bi[rbase];
    float4 bh4 = *(const float4*)&bh[rbase];
    float4 bias = make_float4(bi4.x+bh4.x, bi4.y+bh4.y, bi4.z+bh4.z, bi4.w+bh4.w);
    #pragma unroll
    for (int i = 0; i < 4; i++) {
        int t = by*64 + ty*4 + i;
        float4 v = make_float4(acc[i][0]+bias.x, acc[i][1]+bias.y,
                               acc[i][2]+bias.z, acc[i][3]+bias.w);
        *(float4*)&outp[(size_t)t*G4 + rbase] = v;
    }
}

// ---------------------------------------------------------------------------
// K2: Bi-LSTM recurrence = EXACT round-3 structure (proven 4184us), single
// change: Whh loaded via inline-asm global_load_dwordx4 into OPAQUE registers
// the compiler cannot rematerialize (every prior round's VGPR=84-96 proves
// the "register-resident" weights were silently re-read from L2 each step).
// Protocol: 4-slot canary LLC exchange, all-lane poll with s_sleep(2),
// vmcnt(0) before poll, 2 barriers/step (A: gv ready, D: restage done).
// ---------------------------------------------------------------------------
__global__ __launch_bounds__(512, 2) void k_lstm(
    const float* __restrict__ WhhF, const float* __restrict__ WhhB,
    const float* __restrict__ h0, const float* __restrict__ c0,
    const float* __restrict__ xw,
    float* __restrict__ hbuf, float* __restrict__ hcat)
{
    const int bid = blockIdx.x;
    const int dir = bid >> 4;
    const int w   = bid & 15;
    const float* Whh = dir ? WhhB : WhhF;
    const float* xwD = xw + (size_t)dir*TT*G4;
    float* hb = hbuf + dir*4*HH;        // [slot][HH]

    const int tid  = threadIdx.x;
    const int rl   = tid >> 2;          // 0..127 local row
    const int q    = tid & 3;           // quarter of the K=512 dot
    const int gate = rl >> 5;           // 0:i 1:f 2:g 3:o
    const int jj   = rl & 31;
    const int row  = gate*HH + w*32 + jj;   // global row in [0,2048)

    // Whh quarter-row: 32 x dwordx4 via asm -> values are asm-opaque, MUST
    // stay register-resident (budget 256 VGPR at launch_bounds(512,2))
    f4 wreg[32];
    {
        const f4* wr = (const f4*)&Whh[(size_t)row*HH + q*128];
        #pragma unroll
        for (int k = 0; k < 32; k++)
            asm volatile("global_load_dwordx4 %0, %1, off"
                         : "=v"(wreg[k]) : "v"(wr + k));
        asm volatile("s_waitcnt vmcnt(0)");
    }
    float c = 0.f;
    if (tid < 32) c = c0[dir*HH + w*32 + tid];

    __shared__ __align__(16) float hsh[2064];   // 4 replicas, stride 516 (bank-skewed)
    __shared__ float gv[128];

    {   // initial h (parity 0)
        float hv = h0[dir*HH + tid];
        #pragma unroll
        for (int r = 0; r < 4; r++) hsh[r*516 + tid] = hv;
    }
    __syncthreads();

    const float* hq = &hsh[q*644];      // replica q, offset q*128 folded (516q+128q)

    float xv = 0.f;
    if (q == 0) xv = xwD[(size_t)(dir ? TT-1 : 0)*G4 + row];

    for (int s = 0; s < TT; s++) {
        float p0=0.f,p1=0.f,p2=0.f,p3=0.f;
        #pragma unroll
        for (int k = 0; k < 32; k++) {
            float4 hv = *(const float4*)&hq[4*k];
            p0 += wreg[k].x*hv.x; p1 += wreg[k].y*hv.y;
            p2 += wreg[k].z*hv.z; p3 += wreg[k].w*hv.w;
        }
        float part = (p0+p1)+(p2+p3);
        part += __shfl_xor(part, 1);
        part += __shfl_xor(part, 2);
        if (q == 0) gv[rl] = part + xv;
        __syncthreads();                                   // A: gv ready

        const int time = dir ? (TT-1-s) : s;
        if (tid < 32) {
            const int jc = w*32 + tid;
            float gi = gv[tid], gf = gv[32+tid], gg = gv[64+tid], go = gv[96+tid];
            float i_ = 1.f/(1.f + expf(-gi));
            float f_ = 1.f/(1.f + expf(-gf));
            float g_ = tanhf(gg);
            float o_ = 1.f/(1.f + expf(-go));
            c = f_*c + i_*g_;
            float hn = o_*tanhf(c);
            if (s+1 < TT) {
                __hip_atomic_store(&hb[((s+1)&3)*HH + jc], hn,
                                   __ATOMIC_RELAXED, __HIP_MEMORY_SCOPE_AGENT);
                __hip_atomic_store(&hb[((s+3)&3)*HH + jc], CANARY,
                                   __ATOMIC_RELAXED, __HIP_MEMORY_SCOPE_AGENT);
            }
            hcat[(size_t)time*1024 + dir*HH + jc] = hn;
        }

        if (s+1 < TT) {
            // all of this wave's stores (h + canary reset) at LLC before we
            // can possibly observe anyone's next-gen data
            asm volatile("s_waitcnt vmcnt(0)" ::: "memory");

            // prefetch next xv while polling
            float xv_next = 0.f;
            if (q == 0) xv_next = xwD[(size_t)(dir ? TT-2-s : s+1)*G4 + row];

            // poll own element of next slot; payload doubles as the flag
            const float* addr = &hb[((s+1)&3)*HH + tid];
            float hv; int guard = 0;
            for (;;) {
                hv = __hip_atomic_load(addr, __ATOMIC_RELAXED,
                                       __HIP_MEMORY_SCOPE_AGENT);
                if (hv != CANARY) break;
                if (++guard > (1<<15)) break;              // fail-visible
                __builtin_amdgcn_s_sleep(2);
            }
            #pragma unroll
            for (int r = 0; r < 4; r++) hsh[r*516 + tid] = hv;
            xv = xv_next;
            __syncthreads();                               // D: restage done
        }
    }
}

// ---------------------------------------------------------------------------
// K3: frames[t][j] = dot(hcat[t], Wout[j]) + bout[j]; one block per t.
// 4-way K-split: 192 active threads (48 rows x 4 quarters) + LDS reduce.
// ---------------------------------------------------------------------------
__global__ __launch_bounds__(256) void k_frames(
    const float* __restrict__ hcat, const float* __restrict__ Wout,
    const float* __restrict__ bout, float* __restrict__ frames)
{
    const int t = blockIdx.x, tid = threadIdx.x;
    __shared__ float hrow[1024];
    __shared__ float partial[4][NTAGS];
    ((float4*)hrow)[tid] = ((const float4*)&hcat[(size_t)t*1024])[tid];
    __syncthreads();
    if (tid < 192) {
        const int j = tid % NTAGS, qq = tid / NTAGS;
        const float4* wr = (const float4*)&Wout[(size_t)j*1024 + qq*256];
        const float4* hh = (const float4*)&hrow[qq*256];
        float acc = 0.f;
        #pragma unroll 16
        for (int e = 0; e < 64; e++) {
            float4 wv = wr[e]; float4 hv = hh[e];
            acc += wv.x*hv.x + wv.y*hv.y + wv.z*hv.z + wv.w*hv.w;
        }
        partial[qq][j] = acc;
    }
    __syncthreads();
    if (tid < NTAGS)
        frames[t*NTAGS + tid] = partial[0][tid] + partial[1][tid]
                              + partial[2][tid] + partial[3][tid] + bout[tid];
}

// ---------------------------------------------------------------------------
// K4: Viterbi scan, ONE barrier per step: alpha held in registers (12 per
// thread); after the barrier each thread redundantly combines the quarter
// maxima for the 12 indices it needs next step (red[] parity-buffered).
// bp written by g==0 threads. First-max tie-breaking matches jnp.argmax.
// Backtrace chased through LDS in 256-row chunks (unchanged).
// ---------------------------------------------------------------------------
#define CH 256
__global__ __launch_bounds__(256) void k_viterbi(
    const float* __restrict__ frames, const float* __restrict__ trans,
    const int* __restrict__ startp, const int* __restrict__ endp,
    unsigned char* __restrict__ bp, float* __restrict__ out)
{
    const int tid = threadIdx.x;
    const int g = tid / NTAGS;        // 0..3 compute, 4 = prefetch, rest idle
    const int j = tid % NTAGS;
    __shared__ float red[2][4][NTAGS];
    __shared__ int   redarg[2][4][NTAGS];
    __shared__ float frbuf[2][NTAGS];
    __shared__ float afinal[NTAGS];
    __shared__ __align__(16) unsigned char bps[CH*NTAGS];   // 12 KB
    __shared__ int s_tag;

    float tr[12];
    float al[12];                     // alpha[t][g*12+u], register-resident
    const int start_tag = *startp;
    if (g < 4) {
        #pragma unroll
        for (int u = 0; u < 12; u++) {
            tr[u] = trans[j*NTAGS + g*12 + u];   // transitions[j][i]
            al[u] = (g*12 + u == start_tag) ? 0.f : -10000.f;
        }
    }
    const bool is_pf = (tid >= 192 && tid < 192 + NTAGS);
    if (is_pf) frbuf[0][tid-192] = frames[tid-192];
    __syncthreads();

    for (int t = 0; t < TT; t++) {
        // phase A: per-quarter best over own 12 i's (for every tag j)
        if (g < 4) {
            float best = -3.0e38f; int barg = 0;
            #pragma unroll
            for (int u = 0; u < 12; u++) {
                float sv = al[u] + tr[u];
                if (sv > best) { best = sv; barg = g*12 + u; }
            }
            red[t&1][g][j] = best; redarg[t&1][g][j] = barg;
        }
        __syncthreads();              // the ONLY barrier per step
        // phase B
        float fpre = 0.f;
        if (is_pf && t+1 < TT) fpre = frames[(t+1)*NTAGS + (tid-192)];
        if (g < 4) {
            if (g == 0) {             // bp for tag j: full cross-quarter argmax
                float b = red[t&1][0][j]; int a = redarg[t&1][0][j];
                #pragma unroll
                for (int g2 = 1; g2 < 4; g2++) {
                    float v2 = red[t&1][g2][j];
                    if (v2 > b) { b = v2; a = redarg[t&1][g2][j]; }
                }
                bp[t*NTAGS + j] = (unsigned char)a;
            }
            // next alpha for own 12 indices (redundant across the 48 j's)
            #pragma unroll
            for (int u = 0; u < 12; u++) {
                const int i = g*12 + u;
                float b = red[t&1][0][i];
                #pragma unroll
                for (int g2 = 1; g2 < 4; g2++) {
                    float v2 = red[t&1][g2][i];
                    if (v2 > b) b = v2;
                }
                al[u] = b + frbuf[t&1][i];
            }
            if (t == TT-1 && j == 0) {
                #pragma unroll
                for (int u = 0; u < 12; u++) afinal[g*12 + u] = al[u];
            }
        }
        if (is_pf && t+1 < TT) frbuf[(t+1)&1][tid-192] = fpre;
    }
    __syncthreads();

    if (tid == 0) {
        const int end_tag = *endp;
        float best = -3.0e38f; int bl = 0;
        for (int j2 = 0; j2 < NTAGS; j2++) {
            float v = afinal[j2] + trans[end_tag*NTAGS + j2];
            if (v > best) { best = v; bl = j2; }
        }
        out[0] = best;
        out[1 + TT - 1] = (float)bl;
        s_tag = bl;
    }
    __syncthreads();

    // chunked backtrace: t = TT-1 .. 1, chunks descending
    for (int base = TT - CH; base >= 0; base -= CH) {
        {   // parallel load of rows [base, base+CH) into LDS (48 B each)
            const float4* srcr = (const float4*)&bp[(size_t)(base + tid)*NTAGS];
            float4* dstr = (float4*)&bps[tid*NTAGS];
            dstr[0] = srcr[0]; dstr[1] = srcr[1]; dstr[2] = srcr[2];
        }
        __syncthreads();
        if (tid == 0) {
            int tag = s_tag;
            const int thi = base + CH - 1;
            const int tlo = (base == 0) ? 1 : base;
            for (int t = thi; t >= tlo; t--) {
                tag = bps[(t - base)*NTAGS + tag];
                out[t] = (float)tag;
            }
            s_tag = tag;
        }
        __syncthreads();
    }
}

extern "C" void kernel_launch(void* const* d_in, const int* in_sizes, int n_in,
                              void* d_out, int out_size, void* d_ws, size_t ws_size,
                              hipStream_t stream)
{
    const int*   words = (const int*)  d_in[0];
    const float* embed = (const float*)d_in[1];
    const float* WihF  = (const float*)d_in[2];
    const float* WhhF  = (const float*)d_in[3];
    const float* bihF  = (const float*)d_in[4];
    const float* bhhF  = (const float*)d_in[5];
    const float* WihB  = (const float*)d_in[6];
    const float* WhhB  = (const float*)d_in[7];
    const float* bihB  = (const float*)d_in[8];
    const float* bhhB  = (const float*)d_in[9];
    const float* Wout  = (const float*)d_in[10];
    const float* bout  = (const float*)d_in[11];
    const float* trans = (const float*)d_in[12];
    const float* h0    = (const float*)d_in[13];
    const float* c0    = (const float*)d_in[14];
    const int*   startp= (const int*)  d_in[15];
    const int*   endp  = (const int*)  d_in[16];

    char* ws = (char*)d_ws;
    float* xw   = (float*)(ws + OFF_XW);
    float* hcat = (float*)(ws + OFF_HCAT);
    float* frm  = (float*)(ws + OFF_FRM);
    float* hbuf = (float*)(ws + OFF_HBUF);
    unsigned char* bp = (unsigned char*)(ws + OFF_BP);

    dim3 g1(32, 32, 2);
    k_xw<<<g1, 256, 0, stream>>>(words, embed, WihF, WihB, bihF, bhhF,
                                 bihB, bhhB, xw, hbuf);
    k_lstm<<<dim3(2*NWG), 512, 0, stream>>>(WhhF, WhhB, h0, c0, xw, hbuf, hcat);
    k_frames<<<dim3(TT), 256, 0, stream>>>(hcat, Wout, bout, frm);
    k_viterbi<<<dim3(1), 256, 0, stream>>>(frm, trans, startp, endp, bp, (float*)d_out);
}

// Round 11
// 5241.444 us; speedup vs baseline: 1.6534x; 1.0314x over previous
//
#include <hip/hip_runtime.h>

#define TT 2048
#define HH 512
#define EE 512
#define NTAGS 48
#define G4 2048   // 4*HH
#define NWG 16    // workgroups per direction in the LSTM kernel
#define CANARY 1.0e30f

typedef float f4 __attribute__((ext_vector_type(4)));

// workspace byte offsets
#define OFF_XW    0ULL                                      // [2][TT][G4] f32 = 32 MB
#define OFF_HCAT  (OFF_XW   + 2ULL*TT*G4*4ULL)              // [TT][1024] f32 = 8 MB
#define OFF_FRM   (OFF_HCAT + (unsigned long long)TT*1024ULL*4ULL) // [TT][48] f32
#define OFF_HBUF  (OFF_FRM  + (unsigned long long)TT*NTAGS*4ULL)   // [2][4][HH] f32 (canary slots)
#define OFF_BP    (OFF_HBUF + 2ULL*4ULL*HH*4ULL)            // [TT][48] u8

// fast activations: v_exp_f32 + v_rcp_f32 (rel err ~1e-6; output threshold 106)
__device__ __forceinline__ float fsig(float x) {
    return __builtin_amdgcn_rcpf(1.f + __expf(-x));
}
__device__ __forceinline__ float ftanh(float x) {
    return 1.f - 2.f*__builtin_amdgcn_rcpf(__expf(2.f*x) + 1.f);
}

// ---------------------------------------------------------------------------
// K1: xW[dir][t][r] = sum_e embed[words[t]][e]*Wih[dir][r][e] + bih[r]+bhh[r]
// 64x64 tile, 256 threads, 4x4 micro-tile, K-chunk 32. Also canary-fills the
// LSTM h exchange slots. (unchanged from round 10)
// ---------------------------------------------------------------------------
__global__ __launch_bounds__(256) void k_xw(
    const int* __restrict__ words, const float* __restrict__ embed,
    const float* __restrict__ WihF, const float* __restrict__ WihB,
    const float* __restrict__ bihF, const float* __restrict__ bhhF,
    const float* __restrict__ bihB, const float* __restrict__ bhhB,
    float* __restrict__ xw, float* __restrict__ hbuf)
{
    const int tid = threadIdx.x;
    const int bx = blockIdx.x, by = blockIdx.y, dir = blockIdx.z;

    if (bx == 0 && by == 0) {                   // one block per dir: canary fill
        for (int j = tid; j < 4*HH; j += 256)
            hbuf[dir*4*HH + j] = CANARY;
    }

    const float* Wih = dir ? WihB : WihF;
    const float* bi  = dir ? bihB : bihF;
    const float* bh  = dir ? bhhB : bhhF;

    __shared__ float sa[32][64];
    __shared__ float sb[32][64];
    __shared__ int   wds[64];
    if (tid < 64) wds[tid] = words[by*64 + tid];
    const int tx = tid & 15, ty = tid >> 4;
    float acc[4][4] = {};
    __syncthreads();

    for (int k0 = 0; k0 < EE; k0 += 32) {
        #pragma unroll
        for (int u = 0; u < 2; u++) {
            int idx = tid*2 + u;            // 0..511
            int row = idx >> 3, kq = idx & 7;
            float4 av = *(const float4*)&embed[(size_t)wds[row]*EE + k0 + kq*4];
            float4 bv = *(const float4*)&Wih[(size_t)(bx*64 + row)*EE + k0 + kq*4];
            sa[kq*4+0][row] = av.x; sa[kq*4+1][row] = av.y;
            sa[kq*4+2][row] = av.z; sa[kq*4+3][row] = av.w;
            sb[kq*4+0][row] = bv.x; sb[kq*4+1][row] = bv.y;
            sb[kq*4+2][row] = bv.z; sb[kq*4+3][row] = bv.w;
        }
        __syncthreads();
        #pragma unroll
        for (int k = 0; k < 32; k++) {
            float4 a = *(const float4*)&sa[k][ty*4];
            float4 b = *(const float4*)&sb[k][tx*4];
            acc[0][0] += a.x*b.x; acc[0][1] += a.x*b.y; acc[0][2] += a.x*b.z; acc[0][3] += a.x*b.w;
            acc[1][0] += a.y*b.x; acc[1][1] += a.y*b.y; acc[1][2] += a.y*b.z; acc[1][3] += a.y*b.w;
            acc[2][0] += a.z*b.x; acc[2][1] += a.z*b.y; acc[2][2] += a.z*b.z; acc[2][3] += a.z*b.w;
            acc[3][0] += a.w*b.x; acc[3][1] += a.w*b.y; acc[3][2] += a.w*b.z; acc[3][3] += a.w*b.w;
        }
        __syncthreads();
    }

    float* outp = xw + (size_t)dir*TT*G4;
    const int rbase = bx*64 + tx*4;
    float4 bi4 = *(const float4*)&bi[rbase];
    float4 bh4 = *(const float4*)&bh[rbase];
    float4 bias = make_float4(bi4.x+bh4.x, bi4.y+bh4.y, bi4.z+bh4.z, bi4.w+bh4.w);
    #pragma unroll
    for (int i = 0; i < 4; i++) {
        int t = by*64 + ty*4 + i;
        float4 v = make_float4(acc[i][0]+bias.x, acc[i][1]+bias.y,
                               acc[i][2]+bias.z, acc[i][3]+bias.w);
        *(float4*)&outp[(size_t)t*G4 + rbase] = v;
    }
}

// ---------------------------------------------------------------------------
// K2: Bi-LSTM recurrence = round-10 structure with two critical-path cuts:
//  (1) producer-only vmcnt(0): moved INSIDE the tid<32 block, BEFORE the
//      h/canary stores (drains the 2-step-old canary reset there ~ free).
//      Consumers poll immediately - no more waiting for their own xv
//      prefetch or producers' hcat drain before polling.
//  (2) hardware activations (v_exp_f32 + v_rcp_f32) instead of libm
//      expf/tanhf on the serial 32-lane gate path.
// Protocol otherwise identical: 4-slot canary LLC exchange, all-lane poll
// with s_sleep(2), 2 barriers/step, asm-loaded weights.
// ---------------------------------------------------------------------------
__global__ __launch_bounds__(512, 2) void k_lstm(
    const float* __restrict__ WhhF, const float* __restrict__ WhhB,
    const float* __restrict__ h0, const float* __restrict__ c0,
    const float* __restrict__ xw,
    float* __restrict__ hbuf, float* __restrict__ hcat)
{
    const int bid = blockIdx.x;
    const int dir = bid >> 4;
    const int w   = bid & 15;
    const float* Whh = dir ? WhhB : WhhF;
    const float* xwD = xw + (size_t)dir*TT*G4;
    float* hb = hbuf + dir*4*HH;        // [slot][HH]

    const int tid  = threadIdx.x;
    const int rl   = tid >> 2;          // 0..127 local row
    const int q    = tid & 3;           // quarter of the K=512 dot
    const int gate = rl >> 5;           // 0:i 1:f 2:g 3:o
    const int jj   = rl & 31;
    const int row  = gate*HH + w*32 + jj;   // global row in [0,2048)

    // Whh quarter-row via asm loads (opaque to rematerialization)
    f4 wreg[32];
    {
        const f4* wr = (const f4*)&Whh[(size_t)row*HH + q*128];
        #pragma unroll
        for (int k = 0; k < 32; k++)
            asm volatile("global_load_dwordx4 %0, %1, off"
                         : "=v"(wreg[k]) : "v"(wr + k));
        asm volatile("s_waitcnt vmcnt(0)");
    }
    float c = 0.f;
    if (tid < 32) c = c0[dir*HH + w*32 + tid];

    __shared__ __align__(16) float hsh[2064];   // 4 replicas, stride 516 (bank-skewed)
    __shared__ float gv[128];

    {   // initial h (parity 0)
        float hv = h0[dir*HH + tid];
        #pragma unroll
        for (int r = 0; r < 4; r++) hsh[r*516 + tid] = hv;
    }
    __syncthreads();

    const float* hq = &hsh[q*644];      // replica q, offset q*128 folded (516q+128q)

    float xv = 0.f;
    if (q == 0) xv = xwD[(size_t)(dir ? TT-1 : 0)*G4 + row];

    for (int s = 0; s < TT; s++) {
        float p0=0.f,p1=0.f,p2=0.f,p3=0.f;
        #pragma unroll
        for (int k = 0; k < 32; k++) {
            float4 hv = *(const float4*)&hq[4*k];
            p0 += wreg[k].x*hv.x; p1 += wreg[k].y*hv.y;
            p2 += wreg[k].z*hv.z; p3 += wreg[k].w*hv.w;
        }
        float part = (p0+p1)+(p2+p3);
        part += __shfl_xor(part, 1);
        part += __shfl_xor(part, 2);
        if (q == 0) gv[rl] = part + xv;
        __syncthreads();                                   // A: gv ready

        const int time = dir ? (TT-1-s) : s;
        if (tid < 32) {
            const int jc = w*32 + tid;
            float gi = gv[tid], gf = gv[32+tid], gg = gv[64+tid], go = gv[96+tid];
            float i_ = fsig(gi);
            float f_ = fsig(gf);
            float g_ = ftanh(gg);
            float o_ = fsig(go);
            c = f_*c + i_*g_;
            float hn = o_*ftanh(c);
            if (s+1 < TT) {
                // R1 ordering: this lane's 2-step-old canary reset (same
                // slot as the h store) must be complete. It is ~2 steps
                // stale -> near-free wait; only these 32 lanes pay it.
                asm volatile("s_waitcnt vmcnt(0)" ::: "memory");
                __hip_atomic_store(&hb[((s+1)&3)*HH + jc], hn,
                                   __ATOMIC_RELAXED, __HIP_MEMORY_SCOPE_AGENT);
                __hip_atomic_store(&hb[((s+3)&3)*HH + jc], CANARY,
                                   __ATOMIC_RELAXED, __HIP_MEMORY_SCOPE_AGENT);
            }
            hcat[(size_t)time*1024 + dir*HH + jc] = hn;    // fire-and-forget
        }

        if (s+1 < TT) {
            // consumers: NO pre-poll wait (nothing to order)
            float xv_next = 0.f;
            if (q == 0) xv_next = xwD[(size_t)(dir ? TT-2-s : s+1)*G4 + row];

            // poll own element of next slot; payload doubles as the flag
            const float* addr = &hb[((s+1)&3)*HH + tid];
            float hv; int guard = 0;
            for (;;) {
                hv = __hip_atomic_load(addr, __ATOMIC_RELAXED,
                                       __HIP_MEMORY_SCOPE_AGENT);
                if (hv != CANARY) break;
                if (++guard > (1<<15)) break;              // fail-visible
                __builtin_amdgcn_s_sleep(2);
            }
            #pragma unroll
            for (int r = 0; r < 4; r++) hsh[r*516 + tid] = hv;
            xv = xv_next;
            __syncthreads();                               // D: restage done
        }
    }
}

// ---------------------------------------------------------------------------
// K3: frames[t][j] = dot(hcat[t], Wout[j]) + bout[j]; one block per t.
// 4-way K-split: 192 active threads (48 rows x 4 quarters) + LDS reduce.
// ---------------------------------------------------------------------------
__global__ __launch_bounds__(256) void k_frames(
    const float* __restrict__ hcat, const float* __restrict__ Wout,
    const float* __restrict__ bout, float* __restrict__ frames)
{
    const int t = blockIdx.x, tid = threadIdx.x;
    __shared__ float hrow[1024];
    __shared__ float partial[4][NTAGS];
    ((float4*)hrow)[tid] = ((const float4*)&hcat[(size_t)t*1024])[tid];
    __syncthreads();
    if (tid < 192) {
        const int j = tid % NTAGS, qq = tid / NTAGS;
        const float4* wr = (const float4*)&Wout[(size_t)j*1024 + qq*256];
        const float4* hh = (const float4*)&hrow[qq*256];
        float acc = 0.f;
        #pragma unroll 16
        for (int e = 0; e < 64; e++) {
            float4 wv = wr[e]; float4 hv = hh[e];
            acc += wv.x*hv.x + wv.y*hv.y + wv.z*hv.z + wv.w*hv.w;
        }
        partial[qq][j] = acc;
    }
    __syncthreads();
    if (tid < NTAGS)
        frames[t*NTAGS + tid] = partial[0][tid] + partial[1][tid]
                              + partial[2][tid] + partial[3][tid] + bout[tid];
}

// ---------------------------------------------------------------------------
// K4: Viterbi scan, one barrier per step (round-10 version, unchanged).
// ---------------------------------------------------------------------------
#define CH 256
__global__ __launch_bounds__(256) void k_viterbi(
    const float* __restrict__ frames, const float* __restrict__ trans,
    const int* __restrict__ startp, const int* __restrict__ endp,
    unsigned char* __restrict__ bp, float* __restrict__ out)
{
    const int tid = threadIdx.x;
    const int g = tid / NTAGS;        // 0..3 compute, 4 = prefetch, rest idle
    const int j = tid % NTAGS;
    __shared__ float red[2][4][NTAGS];
    __shared__ int   redarg[2][4][NTAGS];
    __shared__ float frbuf[2][NTAGS];
    __shared__ float afinal[NTAGS];
    __shared__ __align__(16) unsigned char bps[CH*NTAGS];   // 12 KB
    __shared__ int s_tag;

    float tr[12];
    float al[12];                     // alpha[t][g*12+u], register-resident
    const int start_tag = *startp;
    if (g < 4) {
        #pragma unroll
        for (int u = 0; u < 12; u++) {
            tr[u] = trans[j*NTAGS + g*12 + u];   // transitions[j][i]
            al[u] = (g*12 + u == start_tag) ? 0.f : -10000.f;
        }
    }
    const bool is_pf = (tid >= 192 && tid < 192 + NTAGS);
    if (is_pf) frbuf[0][tid-192] = frames[tid-192];
    __syncthreads();

    for (int t = 0; t < TT; t++) {
        if (g < 4) {
            float best = -3.0e38f; int barg = 0;
            #pragma unroll
            for (int u = 0; u < 12; u++) {
                float sv = al[u] + tr[u];
                if (sv > best) { best = sv; barg = g*12 + u; }
            }
            red[t&1][g][j] = best; redarg[t&1][g][j] = barg;
        }
        __syncthreads();              // the ONLY barrier per step
        float fpre = 0.f;
        if (is_pf && t+1 < TT) fpre = frames[(t+1)*NTAGS + (tid-192)];
        if (g < 4) {
            if (g == 0) {             // bp for tag j: full cross-quarter argmax
                float b = red[t&1][0][j]; int a = redarg[t&1][0][j];
                #pragma unroll
                for (int g2 = 1; g2 < 4; g2++) {
                    float v2 = red[t&1][g2][j];
                    if (v2 > b) { b = v2; a = redarg[t&1][g2][j]; }
                }
                bp[t*NTAGS + j] = (unsigned char)a;
            }
            #pragma unroll
            for (int u = 0; u < 12; u++) {
                const int i = g*12 + u;
                float b = red[t&1][0][i];
                #pragma unroll
                for (int g2 = 1; g2 < 4; g2++) {
                    float v2 = red[t&1][g2][i];
                    if (v2 > b) b = v2;
                }
                al[u] = b + frbuf[t&1][i];
            }
            if (t == TT-1 && j == 0) {
                #pragma unroll
                for (int u = 0; u < 12; u++) afinal[g*12 + u] = al[u];
            }
        }
        if (is_pf && t+1 < TT) frbuf[(t+1)&1][tid-192] = fpre;
    }
    __syncthreads();

    if (tid == 0) {
        const int end_tag = *endp;
        float best = -3.0e38f; int bl = 0;
        for (int j2 = 0; j2 < NTAGS; j2++) {
            float v = afinal[j2] + trans[end_tag*NTAGS + j2];
            if (v > best) { best = v; bl = j2; }
        }
        out[0] = best;
        out[1 + TT - 1] = (float)bl;
        s_tag = bl;
    }
    __syncthreads();

    // chunked backtrace: t = TT-1 .. 1, chunks descending
    for (int base = TT - CH; base >= 0; base -= CH) {
        {   // parallel load of rows [base, base+CH) into LDS (48 B each)
            const float4* srcr = (const float4*)&bp[(size_t)(base + tid)*NTAGS];
            float4* dstr = (float4*)&bps[tid*NTAGS];
            dstr[0] = srcr[0]; dstr[1] = srcr[1]; dstr[2] = srcr[2];
        }
        __syncthreads();
        if (tid == 0) {
            int tag = s_tag;
            const int thi = base + CH - 1;
            const int tlo = (base == 0) ? 1 : base;
            for (int t = thi; t >= tlo; t--) {
                tag = bps[(t - base)*NTAGS + tag];
                out[t] = (float)tag;
            }
            s_tag = tag;
        }
        __syncthreads();
    }
}

extern "C" void kernel_launch(void* const* d_in, const int* in_sizes, int n_in,
                              void* d_out, int out_size, void* d_ws, size_t ws_size,
                              hipStream_t stream)
{
    const int*   words = (const int*)  d_in[0];
    const float* embed = (const float*)d_in[1];
    const float* WihF  = (const float*)d_in[2];
    const float* WhhF  = (const float*)d_in[3];
    const float* bihF  = (const float*)d_in[4];
    const float* bhhF  = (const float*)d_in[5];
    const float* WihB  = (const float*)d_in[6];
    const float* WhhB  = (const float*)d_in[7];
    const float* bihB  = (const float*)d_in[8];
    const float* bhhB  = (const float*)d_in[9];
    const float* Wout  = (const float*)d_in[10];
    const float* bout  = (const float*)d_in[11];
    const float* trans = (const float*)d_in[12];
    const float* h0    = (const float*)d_in[13];
    const float* c0    = (const float*)d_in[14];
    const int*   startp= (const int*)  d_in[15];
    const int*   endp  = (const int*)  d_in[16];

    char* ws = (char*)d_ws;
    float* xw   = (float*)(ws + OFF_XW);
    float* hcat = (float*)(ws + OFF_HCAT);
    float* frm  = (float*)(ws + OFF_FRM);
    float* hbuf = (float*)(ws + OFF_HBUF);
    unsigned char* bp = (unsigned char*)(ws + OFF_BP);

    dim3 g1(32, 32, 2);
    k_xw<<<g1, 256, 0, stream>>>(words, embed, WihF, WihB, bihF, bhhF,
                                 bihB, bhhB, xw, hbuf);
    k_lstm<<<dim3(2*NWG), 512, 0, stream>>>(WhhF, WhhB, h0, c0, xw, hbuf, hcat);
    k_frames<<<dim3(TT), 256, 0, stream>>>(hcat, Wout, bout, frm);
    k_viterbi<<<dim3(1), 256, 0, stream>>>(frm, trans, startp, endp, bp, (float*)d_out);
}

// Round 13
// 4819.147 us; speedup vs baseline: 1.7983x; 1.0876x over previous
//
#include <hip/hip_runtime.h>

#define TT 2048
#define HH 512
#define EE 512
#define NTAGS 48
#define G4 2048   // 4*HH
#define NWG 16    // workgroups per direction in the LSTM kernel
#define CANARY 1.0e30f

typedef float f4 __attribute__((ext_vector_type(4)));

// workspace byte offsets
#define OFF_XW    0ULL                                      // [2][TT][G4] f32 = 32 MB
#define OFF_HCAT  (OFF_XW   + 2ULL*TT*G4*4ULL)              // [TT][1024] f32 = 8 MB
#define OFF_FRM   (OFF_HCAT + (unsigned long long)TT*1024ULL*4ULL) // [TT][48] f32
#define OFF_HBUF  (OFF_FRM  + (unsigned long long)TT*NTAGS*4ULL)   // [2][4][HH] f32 (canary slots)
#define OFF_BP    (OFF_HBUF + 2ULL*4ULL*HH*4ULL)            // [TT][48] u8

// fast activations: v_exp_f32 + v_rcp_f32 (rel err ~1e-6; output threshold 106)
__device__ __forceinline__ float fsig(float x) {
    return __builtin_amdgcn_rcpf(1.f + __expf(-x));
}
__device__ __forceinline__ float ftanh(float x) {
    return 1.f - 2.f*__builtin_amdgcn_rcpf(__expf(2.f*x) + 1.f);
}

// ---------------------------------------------------------------------------
// K1: xW[dir][t][r] = sum_e embed[words[t]][e]*Wih[dir][r][e] + bih[r]+bhh[r]
// 64x64 tile, 256 threads, 4x4 micro-tile, K-chunk 32. Also canary-fills the
// LSTM h exchange slots. (unchanged)
// ---------------------------------------------------------------------------
__global__ __launch_bounds__(256) void k_xw(
    const int* __restrict__ words, const float* __restrict__ embed,
    const float* __restrict__ WihF, const float* __restrict__ WihB,
    const float* __restrict__ bihF, const float* __restrict__ bhhF,
    const float* __restrict__ bihB, const float* __restrict__ bhhB,
    float* __restrict__ xw, float* __restrict__ hbuf)
{
    const int tid = threadIdx.x;
    const int bx = blockIdx.x, by = blockIdx.y, dir = blockIdx.z;

    if (bx == 0 && by == 0) {                   // one block per dir: canary fill
        for (int j = tid; j < 4*HH; j += 256)
            hbuf[dir*4*HH + j] = CANARY;
    }

    const float* Wih = dir ? WihB : WihF;
    const float* bi  = dir ? bihB : bihF;
    const float* bh  = dir ? bhhB : bhhF;

    __shared__ float sa[32][64];
    __shared__ float sb[32][64];
    __shared__ int   wds[64];
    if (tid < 64) wds[tid] = words[by*64 + tid];
    const int tx = tid & 15, ty = tid >> 4;
    float acc[4][4] = {};
    __syncthreads();

    for (int k0 = 0; k0 < EE; k0 += 32) {
        #pragma unroll
        for (int u = 0; u < 2; u++) {
            int idx = tid*2 + u;            // 0..511
            int row = idx >> 3, kq = idx & 7;
            float4 av = *(const float4*)&embed[(size_t)wds[row]*EE + k0 + kq*4];
            float4 bv = *(const float4*)&Wih[(size_t)(bx*64 + row)*EE + k0 + kq*4];
            sa[kq*4+0][row] = av.x; sa[kq*4+1][row] = av.y;
            sa[kq*4+2][row] = av.z; sa[kq*4+3][row] = av.w;
            sb[kq*4+0][row] = bv.x; sb[kq*4+1][row] = bv.y;
            sb[kq*4+2][row] = bv.z; sb[kq*4+3][row] = bv.w;
        }
        __syncthreads();
        #pragma unroll
        for (int k = 0; k < 32; k++) {
            float4 a = *(const float4*)&sa[k][ty*4];
            float4 b = *(const float4*)&sb[k][tx*4];
            acc[0][0] += a.x*b.x; acc[0][1] += a.x*b.y; acc[0][2] += a.x*b.z; acc[0][3] += a.x*b.w;
            acc[1][0] += a.y*b.x; acc[1][1] += a.y*b.y; acc[1][2] += a.y*b.z; acc[1][3] += a.y*b.w;
            acc[2][0] += a.z*b.x; acc[2][1] += a.z*b.y; acc[2][2] += a.z*b.z; acc[2][3] += a.z*b.w;
            acc[3][0] += a.w*b.x; acc[3][1] += a.w*b.y; acc[3][2] += a.w*b.z; acc[3][3] += a.w*b.w;
        }
        __syncthreads();
    }

    float* outp = xw + (size_t)dir*TT*G4;
    const int rbase = bx*64 + tx*4;
    float4 bi4 = *(const float4*)&bi[rbase];
    float4 bh4 = *(const float4*)&bh[rbase];
    float4 bias = make_float4(bi4.x+bh4.x, bi4.y+bh4.y, bi4.z+bh4.z, bi4.w+bh4.w);
    #pragma unroll
    for (int i = 0; i < 4; i++) {
        int t = by*64 + ty*4 + i;
        float4 v = make_float4(acc[i][0]+bias.x, acc[i][1]+bias.y,
                               acc[i][2]+bias.z, acc[i][3]+bias.w);
        *(float4*)&outp[(size_t)t*G4 + rbase] = v;
    }
}

// ---------------------------------------------------------------------------
// K2: Bi-LSTM recurrence = round-12 pipelined poll FIXED per learn_hip rule
// #18: hipcc hoists register-only compares past inline-asm s_waitcnt (the
// "memory" clobber doesn't order register reads) -> every counted waitcnt is
// now followed by __builtin_amdgcn_sched_barrier(0). Same for the weight-load
// drain (latent hazard in R10/R11). Everything else identical to round 12:
// 2-deep pipelined poll (sampling ~300cy, no sleep quantization), producer-
// only vmcnt(0), HW activations, 4-slot canary LLC exchange.
// ---------------------------------------------------------------------------
__global__ __launch_bounds__(512, 2) void k_lstm(
    const float* __restrict__ WhhF, const float* __restrict__ WhhB,
    const float* __restrict__ h0, const float* __restrict__ c0,
    const float* __restrict__ xw,
    float* __restrict__ hbuf, float* __restrict__ hcat)
{
    const int bid = blockIdx.x;
    const int dir = bid >> 4;
    const int w   = bid & 15;
    const float* Whh = dir ? WhhB : WhhF;
    const float* xwD = xw + (size_t)dir*TT*G4;
    float* hb = hbuf + dir*4*HH;        // [slot][HH]

    const int tid  = threadIdx.x;
    const int rl   = tid >> 2;          // 0..127 local row
    const int q    = tid & 3;           // quarter of the K=512 dot
    const int gate = rl >> 5;           // 0:i 1:f 2:g 3:o
    const int jj   = rl & 31;
    const int row  = gate*HH + w*32 + jj;   // global row in [0,2048)

    // Whh quarter-row via asm loads (opaque to rematerialization)
    f4 wreg[32];
    {
        const f4* wr = (const f4*)&Whh[(size_t)row*HH + q*128];
        #pragma unroll
        for (int k = 0; k < 32; k++)
            asm volatile("global_load_dwordx4 %0, %1, off"
                         : "=v"(wreg[k]) : "v"(wr + k));
        asm volatile("s_waitcnt vmcnt(0)" ::: "memory");
        __builtin_amdgcn_sched_barrier(0);      // rule #18: pin reads after wait
    }
    float c = 0.f;
    if (tid < 32) c = c0[dir*HH + w*32 + tid];

    __shared__ __align__(16) float hsh[2064];   // 4 replicas, stride 516 (bank-skewed)
    __shared__ float gv[128];

    {   // initial h (parity 0)
        float hv = h0[dir*HH + tid];
        #pragma unroll
        for (int r = 0; r < 4; r++) hsh[r*516 + tid] = hv;
    }
    __syncthreads();

    const float* hq = &hsh[q*644];      // replica q, offset q*128 folded (516q+128q)

    float xv = 0.f;
    if (q == 0) xv = xwD[(size_t)(dir ? TT-1 : 0)*G4 + row];

    for (int s = 0; s < TT; s++) {
        float p0=0.f,p1=0.f,p2=0.f,p3=0.f;
        #pragma unroll
        for (int k = 0; k < 32; k++) {
            float4 hv = *(const float4*)&hq[4*k];
            p0 += wreg[k].x*hv.x; p1 += wreg[k].y*hv.y;
            p2 += wreg[k].z*hv.z; p3 += wreg[k].w*hv.w;
        }
        float part = (p0+p1)+(p2+p3);
        part += __shfl_xor(part, 1);
        part += __shfl_xor(part, 2);
        if (q == 0) gv[rl] = part + xv;
        __syncthreads();                                   // A: gv ready

        const int time = dir ? (TT-1-s) : s;
        if (tid < 32) {
            const int jc = w*32 + tid;
            float gi = gv[tid], gf = gv[32+tid], gg = gv[64+tid], go = gv[96+tid];
            float i_ = fsig(gi);
            float f_ = fsig(gf);
            float g_ = ftanh(gg);
            float o_ = fsig(go);
            c = f_*c + i_*g_;
            float hn = o_*ftanh(c);
            if (s+1 < TT) {
                // R1 ordering: this lane's 2-step-old canary reset (same
                // slot as the h store) must be complete. Near-free wait.
                asm volatile("s_waitcnt vmcnt(0)" ::: "memory");
                __hip_atomic_store(&hb[((s+1)&3)*HH + jc], hn,
                                   __ATOMIC_RELAXED, __HIP_MEMORY_SCOPE_AGENT);
                __hip_atomic_store(&hb[((s+3)&3)*HH + jc], CANARY,
                                   __ATOMIC_RELAXED, __HIP_MEMORY_SCOPE_AGENT);
            }
            hcat[(size_t)time*1024 + dir*HH + jc] = hn;    // fire-and-forget
        }

        if (s+1 < TT) {
            float xv_next = 0.f;
            if (q == 0) xv_next = xwD[(size_t)(dir ? TT-2-s : s+1)*G4 + row];

            // 2-deep pipelined poll of own element (payload IS the flag).
            // Every counted waitcnt is fenced with sched_barrier(0) so the
            // compare cannot be hoisted before the load completes (rule #18).
            const float* addr = &hb[((s+1)&3)*HH + tid];
            float va, vb = CANARY; int guard = 0;
            asm volatile("global_load_dword %0, %1, off sc1"
                         : "=v"(va) : "v"(addr));
            for (;;) {
                asm volatile("global_load_dword %0, %1, off sc1"
                             : "=v"(vb) : "v"(addr));
                asm volatile("s_waitcnt vmcnt(1)" ::: "memory");   // va ready
                __builtin_amdgcn_sched_barrier(0);
                if (va != CANARY) break;
                asm volatile("global_load_dword %0, %1, off sc1"
                             : "=v"(va) : "v"(addr));
                asm volatile("s_waitcnt vmcnt(1)" ::: "memory");   // vb ready
                __builtin_amdgcn_sched_barrier(0);
                if (vb != CANARY) break;
                if (++guard > (1<<14)) break;              // fail-visible
            }
            asm volatile("s_waitcnt vmcnt(0)" ::: "memory");       // drain in-flight
            __builtin_amdgcn_sched_barrier(0);
            // slot value is canary->h monotone within this occupancy, so any
            // non-canary register holds h regardless of completion order
            float hv = (va != CANARY) ? va : vb;
            #pragma unroll
            for (int r = 0; r < 4; r++) hsh[r*516 + tid] = hv;
            xv = xv_next;
            __syncthreads();                               // D: restage done
        }
    }
}

// ---------------------------------------------------------------------------
// K3: frames[t][j] = dot(hcat[t], Wout[j]) + bout[j]; one block per t.
// (round-3 64-thread version — proven fastest via others-time subtraction)
// ---------------------------------------------------------------------------
__global__ __launch_bounds__(64) void k_frames(
    const float* __restrict__ hcat, const float* __restrict__ Wout,
    const float* __restrict__ bout, float* __restrict__ frames)
{
    const int t = blockIdx.x, tid = threadIdx.x;
    __shared__ float hrow[1024];
    const float4* src  = (const float4*)&hcat[(size_t)t*1024];
    float4* dst4 = (float4*)hrow;
    #pragma unroll
    for (int u = 0; u < 4; u++) dst4[u*64 + tid] = src[u*64 + tid];
    __syncthreads();
    if (tid < NTAGS) {
        float acc = bout[tid];
        const float4* wr = (const float4*)&Wout[(size_t)tid*1024];
        #pragma unroll 16
        for (int e = 0; e < 256; e++) {
            float4 wv = wr[e];
            float4 hv = dst4[e];
            acc += wv.x*hv.x + wv.y*hv.y + wv.z*hv.z + wv.w*hv.w;
        }
        frames[t*NTAGS + tid] = acc;
    }
}

// ---------------------------------------------------------------------------
// K4: Viterbi scan (round-3 version: 2 barriers/step, alpha in LDS)
// + backtrace chased through LDS in 256-row chunks.
// First-max tie-breaking matches jnp.argmax (ascending i, strict >).
// ---------------------------------------------------------------------------
#define CH 256
__global__ __launch_bounds__(256) void k_viterbi(
    const float* __restrict__ frames, const float* __restrict__ trans,
    const int* __restrict__ startp, const int* __restrict__ endp,
    unsigned char* __restrict__ bp, float* __restrict__ out)
{
    const int tid = threadIdx.x;
    const int grp = tid / NTAGS;      // 0..3 compute, 4 = prefetch, rest idle
    const int j   = tid % NTAGS;
    __shared__ float alpha[2][NTAGS];
    __shared__ float red[4][NTAGS];
    __shared__ int   redarg[4][NTAGS];
    __shared__ float frbuf[2][NTAGS];
    __shared__ __align__(16) unsigned char bps[CH*NTAGS];   // 12 KB
    __shared__ int s_tag;

    float tr[12];
    if (grp < 4) {
        #pragma unroll
        for (int u = 0; u < 12; u++) tr[u] = trans[j*NTAGS + grp*12 + u]; // transitions[j][i]
    }
    const int start_tag = *startp;
    if (tid < NTAGS) alpha[0][tid] = (tid == start_tag) ? 0.f : -10000.f;
    const bool is_pf = (tid >= 192 && tid < 192 + NTAGS);
    if (is_pf) frbuf[0][tid-192] = frames[tid-192];
    __syncthreads();

    for (int t = 0; t < TT; t++) {
        float fpre = 0.f;
        if (is_pf && t+1 < TT) fpre = frames[(t+1)*NTAGS + (tid-192)];
        if (grp < 4) {
            float best = -3.0e38f; int barg = 0;
            #pragma unroll
            for (int u = 0; u < 12; u++) {
                float sv = alpha[t&1][grp*12+u] + tr[u];
                if (sv > best) { best = sv; barg = grp*12+u; }
            }
            red[grp][j] = best; redarg[grp][j] = barg;
        }
        __syncthreads();
        if (tid < NTAGS) {
            float b = red[0][tid]; int a = redarg[0][tid];
            #pragma unroll
            for (int g2 = 1; g2 < 4; g2++) {
                float v = red[g2][tid];
                if (v > b) { b = v; a = redarg[g2][tid]; }
            }
            bp[t*NTAGS + tid] = (unsigned char)a;
            alpha[(t+1)&1][tid] = b + frbuf[t&1][tid];
        }
        __syncthreads();
        if (is_pf && t+1 < TT) frbuf[(t+1)&1][tid-192] = fpre;
    }

    if (tid == 0) {
        const int end_tag = *endp;
        float best = -3.0e38f; int bl = 0;
        for (int j2 = 0; j2 < NTAGS; j2++) {
            float v = alpha[0][j2] + trans[end_tag*NTAGS + j2];  // TT even -> parity 0
            if (v > best) { best = v; bl = j2; }
        }
        out[0] = best;
        out[1 + TT - 1] = (float)bl;
        s_tag = bl;
    }
    __syncthreads();

    // chunked backtrace: t = TT-1 .. 1, chunks descending
    for (int base = TT - CH; base >= 0; base -= CH) {
        {   // parallel load of rows [base, base+CH) into LDS (48 B each)
            const float4* srcr = (const float4*)&bp[(size_t)(base + tid)*NTAGS];
            float4* dstr = (float4*)&bps[tid*NTAGS];
            dstr[0] = srcr[0]; dstr[1] = srcr[1]; dstr[2] = srcr[2];
        }
        __syncthreads();
        if (tid == 0) {
            int tag = s_tag;
            const int thi = base + CH - 1;
            const int tlo = (base == 0) ? 1 : base;
            for (int t = thi; t >= tlo; t--) {
                tag = bps[(t - base)*NTAGS + tag];
                out[t] = (float)tag;
            }
            s_tag = tag;
        }
        __syncthreads();
    }
}

extern "C" void kernel_launch(void* const* d_in, const int* in_sizes, int n_in,
                              void* d_out, int out_size, void* d_ws, size_t ws_size,
                              hipStream_t stream)
{
    const int*   words = (const int*)  d_in[0];
    const float* embed = (const float*)d_in[1];
    const float* WihF  = (const float*)d_in[2];
    const float* WhhF  = (const float*)d_in[3];
    const float* bihF  = (const float*)d_in[4];
    const float* bhhF  = (const float*)d_in[5];
    const float* WihB  = (const float*)d_in[6];
    const float* WhhB  = (const float*)d_in[7];
    const float* bihB  = (const float*)d_in[8];
    const float* bhhB  = (const float*)d_in[9];
    const float* Wout  = (const float*)d_in[10];
    const float* bout  = (const float*)d_in[11];
    const float* trans = (const float*)d_in[12];
    const float* h0    = (const float*)d_in[13];
    const float* c0    = (const float*)d_in[14];
    const int*   startp= (const int*)  d_in[15];
    const int*   endp  = (const int*)  d_in[16];

    char* ws = (char*)d_ws;
    float* xw   = (float*)(ws + OFF_XW);
    float* hcat = (float*)(ws + OFF_HCAT);
    float* frm  = (float*)(ws + OFF_FRM);
    float* hbuf = (float*)(ws + OFF_HBUF);
    unsigned char* bp = (unsigned char*)(ws + OFF_BP);

    dim3 g1(32, 32, 2);
    k_xw<<<g1, 256, 0, stream>>>(words, embed, WihF, WihB, bihF, bhhF,
                                 bihB, bhhB, xw, hbuf);
    k_lstm<<<dim3(2*NWG), 512, 0, stream>>>(WhhF, WhhB, h0, c0, xw, hbuf, hcat);
    k_frames<<<dim3(TT), 64, 0, stream>>>(hcat, Wout, bout, frm);
    k_viterbi<<<dim3(1), 256, 0, stream>>>(frm, trans, startp, endp, bp, (float*)d_out);
}